// Round 3
// baseline (208.332 us; speedup 1.0000x reference)
//
#include <hip/hip_runtime.h>
#include <hip/hip_bf16.h>

// Problem constants
#define B_   2
#define T_   2048
#define D_   1024
#define NH_  16
#define HD_  64
#define MROWS (B_*T_)              // 4096
#define HEADELEMS (B_*NH_*T_*HD_)  // 4194304 per Q/K/V tensor

// exp(s/8) = 2^(s * 0.125 * log2 e); folded into Q at the QKV epilogue
#define QSCALE 0.180336880f

typedef unsigned short u16;
typedef unsigned int   u32;

typedef float f32x4  __attribute__((ext_vector_type(4)));
typedef short bf16x8 __attribute__((ext_vector_type(8)));

// async global->LDS, 16 B/lane; LDS dest = wave-uniform base + lane*16
#define GLP(g, l) __builtin_amdgcn_global_load_lds(                         \
    (const __attribute__((address_space(1))) void*)(g),                     \
    (__attribute__((address_space(3))) void*)(l), 16, 0, 0)

struct Fc { static constexpr bool value = false; };
struct Tc { static constexpr bool value = true;  };

__device__ __forceinline__ u16 f2bf(float f) {
    u32 x = __float_as_uint(f);
    u32 r = (x + 0x7fffu + ((x >> 16) & 1u)) >> 16;
    return (u16)r;
}
// packed fp32x2 -> bf16x2
__device__ __forceinline__ u32 pkbf2(float a, float b) {
    __hip_bfloat162 h = __float22bfloat162_rn(make_float2(a, b));
    union { __hip_bfloat162 h2; u32 u; } cv; cv.h2 = h; return cv.u;
}

// ---------------------------------------------------------------------------
// Fused prep: [0,4096) x fp32->bf16; [4096,4864) Wqkv -> bf16 T;
// [4864,5120) Wproj -> bf16 T (only launched on the huge-ws path).
// ---------------------------------------------------------------------------
__device__ __forceinline__ void transpose_tile(const float* in, u16* out,
                                               int K, int N, int bx, int by,
                                               int t, float (*Ts)[65])
{
    const int n0 = bx * 64;
    const int k0 = by * 64;
    #pragma unroll
    for (int pass = 0; pass < 4; pass++) {
        const int r = pass * 16 + (t >> 4);
        const int c = (t & 15) * 4;
        float4 v = *(const float4*)(in + (size_t)(k0 + r) * N + n0 + c);
        Ts[r][c] = v.x; Ts[r][c+1] = v.y; Ts[r][c+2] = v.z; Ts[r][c+3] = v.w;
    }
    __syncthreads();
    #pragma unroll
    for (int pass = 0; pass < 2; pass++) {
        const int nn = pass * 32 + (t >> 3);
        const int kk = (t & 7) * 8;
        u16 o[8];
        #pragma unroll
        for (int j = 0; j < 8; j++) o[j] = f2bf(Ts[kk + j][nn]);
        *(uint4*)(out + (size_t)(n0 + nn) * K + k0 + kk) = *(const uint4*)o;
    }
}

__global__ __launch_bounds__(256)
void prep_kernel(const float* __restrict__ x, const float* __restrict__ Wqkv,
                 const float* __restrict__ Wproj, u16* __restrict__ xb,
                 u16* __restrict__ WqkvT, u16* __restrict__ WprojT)
{
    __shared__ float Ts[64][65];
    const int bid = blockIdx.x;
    const int t   = threadIdx.x;
    if (bid < 4096) {
        int i = bid * 256 + t;
        float4 v = ((const float4*)x)[i];
        ushort4 o;
        o.x = f2bf(v.x); o.y = f2bf(v.y); o.z = f2bf(v.z); o.w = f2bf(v.w);
        ((ushort4*)xb)[i] = o;
    } else if (bid < 4096 + 768) {
        int tb = bid - 4096;                   // [3072][1024] T
        transpose_tile(Wqkv, WqkvT, D_, 3*D_, tb % 48, tb / 48, t, Ts);
    } else {
        int tb = bid - 4864;                   // [1024][1024] T
        transpose_tile(Wproj, WprojT, D_, D_, tb % 16, tb / 16, t, Ts);
    }
}

__global__ __launch_bounds__(256)
void transpose_conv_kernel(const float* __restrict__ in, u16* __restrict__ out,
                           int K, int N)
{
    __shared__ float Ts[64][65];
    transpose_tile(in, out, K, N, blockIdx.x, blockIdx.y, threadIdx.x, Ts);
}

// ---------------------------------------------------------------------------
// MFMA GEMM. Round-13 change: OCCUPANCY, not pipelining. Tile 64x128 with
// 2-wave (128-thread) blocks; per-wave geometry identical to the proven
// 128x128/4-wave version (64x64 output, 4 A-frag + 4 B-frag ds_reads, 16
// MFMAs per BK=32 step), but grid = 1536 blocks (QKV) -> 6 blocks/CU
// (was 3). Inter-block TLP is the latency-hiding mechanism on this
// structure (r1 post-mortem: explicit dbuf lost occupancy and regressed);
// doubling co-resident blocks follows the m102 shape curve (1/CU=320TF,
// 4/CU=833TF). Single-buffer LDS (12 KB), 2 barriers per K-step, r0 sched.
// MODE 0: fp32 row-major + bias. MODE 1: scatter bf16 Q(*QSCALE),K | V^T
// (uint2-packed along t).
// ---------------------------------------------------------------------------
template <int MODE>
__global__ __launch_bounds__(128)
void gemm_mfma(const u16* __restrict__ A, const u16* __restrict__ BT,
               const float* __restrict__ bias, void* __restrict__ outv,
               int M, int N, int K)
{
    __shared__ u16 As[64][32];
    __shared__ u16 Bs[128][32];

    const int t    = threadIdx.x;
    const int wave = t >> 6;           // 0..1
    const int lane = t & 63;
    const int l16  = lane & 15;
    const int quad = lane >> 4;

    const int m0 = blockIdx.y * 64;
    const int n0 = blockIdx.x * 128;
    const int nb = wave * 64;          // wave's n-half of the 128-wide tile

    // staging: 16 rows/GLP (4 lanes x 8 elems per row), XOR segment swizzle.
    // All GLP groups share one seg value: rows differ by multiples of 16,
    // so ((row>>1)&3) == ((lane>>3)&3) for every group.
    const int lrow = lane >> 2;                          // 0..15
    const int seg  = (((lane & 3) ^ ((lane >> 3) & 3))) * 8;

    const int ra0 = wave * 32;          // A rows [wave*32, +16)
    const int ra1 = wave * 32 + 16;     // A rows [wave*32+16, +16)
    const int rb0 = wave * 64;          // B rows [wave*64, +64) in 4 GLPs

    const u16* gA0 = A  + (size_t)(m0 + ra0 + lrow) * K + seg;
    const u16* gA1 = A  + (size_t)(m0 + ra1 + lrow) * K + seg;
    const u16* gB0 = BT + (size_t)(n0 + rb0      + lrow) * K + seg;
    const u16* gB1 = BT + (size_t)(n0 + rb0 + 16 + lrow) * K + seg;
    const u16* gB2 = BT + (size_t)(n0 + rb0 + 32 + lrow) * K + seg;
    const u16* gB3 = BT + (size_t)(n0 + rb0 + 48 + lrow) * K + seg;

    const int fragoff = (quad ^ ((l16 >> 1) & 3)) * 8;

    f32x4 acc[4][4];
    #pragma unroll
    for (int i = 0; i < 4; i++)
        #pragma unroll
        for (int j = 0; j < 4; j++) acc[i][j] = (f32x4){0,0,0,0};

    for (int k0 = 0; k0 < K; k0 += 32) {
        __syncthreads();
        GLP(gA0 + k0, &As[ra0][0]);
        GLP(gA1 + k0, &As[ra1][0]);
        GLP(gB0 + k0, &Bs[rb0][0]);
        GLP(gB1 + k0, &Bs[rb0 + 16][0]);
        GLP(gB2 + k0, &Bs[rb0 + 32][0]);
        GLP(gB3 + k0, &Bs[rb0 + 48][0]);
        __syncthreads();

        bf16x8 af[4], bfr[4];
        #pragma unroll
        for (int i = 0; i < 4; i++)
            af[i] = *(const bf16x8*)&As[i*16 + l16][fragoff];
        #pragma unroll
        for (int j = 0; j < 4; j++)
            bfr[j] = *(const bf16x8*)&Bs[nb + j*16 + l16][fragoff];

        #pragma unroll
        for (int i = 0; i < 4; i++)
            #pragma unroll
            for (int j = 0; j < 4; j++)
                acc[i][j] = __builtin_amdgcn_mfma_f32_16x16x32_bf16(
                    af[i], bfr[j], acc[i][j], 0, 0, 0);
    }

    if (MODE == 0) {
        #pragma unroll
        for (int j = 0; j < 4; j++) {
            const int n = n0 + nb + j*16 + l16;
            const float bv = bias[n];
            #pragma unroll
            for (int i = 0; i < 4; i++) {
                #pragma unroll
                for (int r = 0; r < 4; r++) {
                    const int m = m0 + i*16 + quad*4 + r;
                    ((float*)outv)[(size_t)m * N + n] = acc[i][j][r] + bv;
                }
            }
        }
    } else {
        const int sec = n0 >> 10;        // block-uniform: 0=q 1=k 2=v
        const int b   = m0 >> 11;        // block-uniform batch index
        const int tb  = m0 & 2047;
        if (sec < 2) {
            // Q/K: [b,h,t,hd] layout; hd = l16-contiguous (32B runs)
            const float qs = (sec == 0) ? QSCALE : 1.f;
            #pragma unroll
            for (int j = 0; j < 4; j++) {
                const int n  = n0 + nb + j*16 + l16;
                const float bv = bias[n];
                const int dd = n & 1023;
                const int h  = dd >> 6;
                const int hd = dd & 63;
                u16* op = (u16*)outv + (size_t)sec * HEADELEMS
                        + ((size_t)(b*NH_ + h)) * T_ * HD_ + hd;
                #pragma unroll
                for (int i = 0; i < 4; i++) {
                    #pragma unroll
                    for (int r = 0; r < 4; r++) {
                        const int tt = tb + i*16 + quad*4 + r;
                        op[(size_t)tt * HD_] = f2bf((acc[i][j][r] + bv) * qs);
                    }
                }
            }
        } else {
            // V^T: [b,h,hd,t] layout; 4 consecutive r == consecutive tt ->
            // one 8B store each
            #pragma unroll
            for (int j = 0; j < 4; j++) {
                const int n  = n0 + nb + j*16 + l16;
                const float bv = bias[n];
                const int dd = n & 1023;
                const int h  = dd >> 6;
                const int hd = dd & 63;
                u16* vp = (u16*)outv + (size_t)2 * HEADELEMS
                        + ((size_t)(b*NH_ + h)) * T_ * HD_
                        + (size_t)hd * T_ + tb;
                #pragma unroll
                for (int i = 0; i < 4; i++) {
                    u16 o[4];
                    #pragma unroll
                    for (int r = 0; r < 4; r++) o[r] = f2bf(acc[i][j][r] + bv);
                    *(uint2*)(vp + i*16 + quad*4) = *(const uint2*)o;
                }
            }
        }
    }
}

// ---------------------------------------------------------------------------
// MFMA flash attention v6 (causal, no-max softmax; scores bounded ~2.5).
// 64 q-rows/block (16/wave), grid (hb=32, y=32) = 1024 blocks -> 4 blocks/CU
// (LDS 36.9 KB fits exactly 4). Co-resident blocks {yy,yy+8,yy+16,yy+24}
// get qt {31-a,16+a,15-a,a} -> constant 62 tiles/CU. In-register C->A
// shuffle redistribution, ones-MFMA row sums, compile-time masked-tile
// split. T5 s_setprio(1) around the MFMA clusters (blocks on one CU run at
// independent phases -> scheduler favors MFMA-issuing waves; m191 +4-7%).
// ---------------------------------------------------------------------------
__global__ __launch_bounds__(256)
void attn_mfma_kernel(const u16* __restrict__ Q, const u16* __restrict__ K,
                      const u16* __restrict__ VT, u16* __restrict__ y1)
{
    __shared__ u16 Ks[2][64][72];     // [buf][key][d]
    __shared__ u16 Vs[2][64][72];     // [buf][d][key]

    const int t    = threadIdx.x;
    const int wave = t >> 6;
    const int lane = t & 63;
    const int l16  = lane & 15;
    const int quad = lane >> 4;

    const int hb = blockIdx.x;                 // b*NH + h (XCD-pinned)
    const int yy = blockIdx.y;
    const int a  = yy & 7, g = yy >> 3;
    const int qt = (g == 0) ? 31 - a : (g == 1) ? 16 + a
                 : (g == 2) ? 15 - a : a;      // balanced 4-way pairing
    const int b  = hb >> 4;
    const int h  = hb & 15;
    const size_t base = (size_t)hb * T_ * HD_;

    const int qw0 = qt * 64 + wave * 16;       // first q-row of this wave

    // Q fragment: 2 d-chunks (Q pre-scaled by QSCALE)
    bf16x8 qf[2];
    {
        const u16* qp = Q + base + (size_t)(qw0 + l16) * HD_ + quad * 8;
        qf[0] = *(const bf16x8*)(qp);
        qf[1] = *(const bf16x8*)(qp + 32);
    }

    bf16x8 onesf;
    #pragma unroll
    for (int i = 0; i < 8; i++) onesf[i] = (short)0x3F80;

    f32x4 o[4];
    #pragma unroll
    for (int d = 0; d < 4; d++) o[d] = (f32x4){0,0,0,0};
    f32x4 accl = (f32x4){0,0,0,0};

    const int nsteps = qt + 1;                 // uniform across waves;
                                               // fullw = qt, masked = last

    const int srow = t >> 3;
    const int scol = (t & 7) * 8;

    // shuffle sources for C->A redistribution (r10-verified)
    const int srcA  = l16 + ((quad & 1) << 5);
    const int srcB  = srcA + 16;
    const bool selhi = (quad >> 1) != 0;

    // stage tile 0
    uint4 kr0, kr1, vr0, vr1;
    {
        const u16* kp = K + base + (size_t)srow * HD_ + scol;
        kr0 = *(const uint4*)kp;
        kr1 = *(const uint4*)(kp + 32 * HD_);
        const u16* vp = VT + base + (size_t)srow * T_ + scol;
        vr0 = *(const uint4*)vp;
        vr1 = *(const uint4*)(vp + 32 * T_);
        *(uint4*)&Ks[0][srow][scol]      = kr0;
        *(uint4*)&Ks[0][srow + 32][scol] = kr1;
        *(uint4*)&Vs[0][srow][scol]      = vr0;
        *(uint4*)&Vs[0][srow + 32][scol] = vr1;
    }
    __syncthreads();

    auto compute_tile = [&](int cur, int k0, auto mc) {
        constexpr bool MASKED = decltype(mc)::value;
        // S^T = K_tile . Q^T
        f32x4 st[4];
        __builtin_amdgcn_s_setprio(1);
        #pragma unroll
        for (int j = 0; j < 4; j++) {
            bf16x8 kf0 = *(const bf16x8*)&Ks[cur][j*16 + l16][quad * 8];
            bf16x8 kf1 = *(const bf16x8*)&Ks[cur][j*16 + l16][32 + quad * 8];
            f32x4 z = {0,0,0,0};
            z = __builtin_amdgcn_mfma_f32_16x16x32_bf16(kf0, qf[0], z, 0, 0, 0);
            st[j] = __builtin_amdgcn_mfma_f32_16x16x32_bf16(kf1, qf[1], z, 0, 0, 0);
        }
        __builtin_amdgcn_s_setprio(0);

        // exp2 (+ mask, compile-time gated) + packed bf16
        u32 p01[4], p23[4];
        const int qi = qw0 + l16;
        #pragma unroll
        for (int j = 0; j < 4; j++) {
            const int kb = k0 + j*16 + quad*4;
            float e0 = __builtin_amdgcn_exp2f(st[j][0]);
            float e1 = __builtin_amdgcn_exp2f(st[j][1]);
            float e2 = __builtin_amdgcn_exp2f(st[j][2]);
            float e3 = __builtin_amdgcn_exp2f(st[j][3]);
            if (MASKED) {
                if (kb + 0 > qi) e0 = 0.f;
                if (kb + 1 > qi) e1 = 0.f;
                if (kb + 2 > qi) e2 = 0.f;
                if (kb + 3 > qi) e3 = 0.f;
            }
            p01[j] = pkbf2(e0, e1);
            p23[j] = pkbf2(e2, e3);
        }

        // C->A redistribution via shuffles; then ones-MFMA + PV
        bf16x8 pf[2];
        #pragma unroll
        for (int c = 0; c < 2; c++) {
            u32 t0, t1, r01, r23, r45, r67;
            t0 = (u32)__shfl((int)p01[2*c],   srcA);
            t1 = (u32)__shfl((int)p01[2*c+1], srcA);
            r01 = selhi ? t1 : t0;
            t0 = (u32)__shfl((int)p23[2*c],   srcA);
            t1 = (u32)__shfl((int)p23[2*c+1], srcA);
            r23 = selhi ? t1 : t0;
            t0 = (u32)__shfl((int)p01[2*c],   srcB);
            t1 = (u32)__shfl((int)p01[2*c+1], srcB);
            r45 = selhi ? t1 : t0;
            t0 = (u32)__shfl((int)p23[2*c],   srcB);
            t1 = (u32)__shfl((int)p23[2*c+1], srcB);
            r67 = selhi ? t1 : t0;
            union { u32 u[4]; bf16x8 v; } pk;
            pk.u[0] = r01; pk.u[1] = r23; pk.u[2] = r45; pk.u[3] = r67;
            pf[c] = pk.v;
        }
        __builtin_amdgcn_s_setprio(1);
        accl = __builtin_amdgcn_mfma_f32_16x16x32_bf16(pf[0], onesf, accl, 0, 0, 0);
        accl = __builtin_amdgcn_mfma_f32_16x16x32_bf16(pf[1], onesf, accl, 0, 0, 0);
        #pragma unroll
        for (int d = 0; d < 4; d++) {
            bf16x8 v0 = *(const bf16x8*)&Vs[cur][d*16 + l16][quad * 8];
            bf16x8 v1 = *(const bf16x8*)&Vs[cur][d*16 + l16][32 + quad * 8];
            o[d] = __builtin_amdgcn_mfma_f32_16x16x32_bf16(pf[0], v0, o[d], 0, 0, 0);
            o[d] = __builtin_amdgcn_mfma_f32_16x16x32_bf16(pf[1], v1, o[d], 0, 0, 0);
        }
        __builtin_amdgcn_s_setprio(0);
    };

    for (int kt = 0; kt < nsteps; kt++) {
        const int cur = kt & 1;
        const int k0  = kt * 64;
        const bool have_next = (kt + 1 < nsteps);

        if (have_next) {
            const u16* kp = K + base + (size_t)(k0 + 64 + srow) * HD_ + scol;
            kr0 = *(const uint4*)kp;
            kr1 = *(const uint4*)(kp + 32 * HD_);
            const u16* vp = VT + base + (size_t)srow * T_ + k0 + 64 + scol;
            vr0 = *(const uint4*)vp;
            vr1 = *(const uint4*)(vp + 32 * T_);
        }

        if (kt < qt) compute_tile(cur, k0, Fc{});
        else         compute_tile(cur, k0, Tc{});

        if (have_next) {
            const int nxt = cur ^ 1;
            *(uint4*)&Ks[nxt][srow][scol]      = kr0;
            *(uint4*)&Ks[nxt][srow + 32][scol] = kr1;
            *(uint4*)&Vs[nxt][srow][scol]      = vr0;
            *(uint4*)&Vs[nxt][srow + 32][scol] = vr1;
            __syncthreads();
        }
    }

    // epilogue: normalize by ones-MFMA row sums; y1[B,T,D] bf16
    #pragma unroll
    for (int r = 0; r < 4; r++) {
        const float inv = 1.f / accl[r];
        const int qi = qw0 + quad*4 + r;
        u16* yp = y1 + ((size_t)(b * T_ + qi)) * D_ + h * HD_ + l16;
        yp[0]  = f2bf(o[0][r] * inv);
        yp[16] = f2bf(o[1][r] * inv);
        yp[32] = f2bf(o[2][r] * inv);
        yp[48] = f2bf(o[3][r] * inv);
    }
}

// ---------------------------------------------------------------------------
// Choreography, three ws tiers:
//  huge (>= 3*QKV + y1 + WprojT = ~35.7 MB): prep also transposes Wproj into
//    ws; attn -> y1 in ws; 4 dispatches, no memcpy.
//  big  (>= 3*QKV + y1 = ~33.5 MB): y1 in ws; WprojT over dead K after attn.
//  small: y1 over dead xb in d_out; memcpy to dead VT; WprojT over dead K.
// ---------------------------------------------------------------------------
extern "C" void kernel_launch(void* const* d_in, const int* in_sizes, int n_in,
                              void* d_out, int out_size, void* d_ws, size_t ws_size,
                              hipStream_t stream)
{
    const float* x     = (const float*)d_in[0];
    const float* Wqkv  = (const float*)d_in[1];
    const float* bqkv  = (const float*)d_in[2];
    const float* Wproj = (const float*)d_in[3];
    const float* bproj = (const float*)d_in[4];

    u16* scratch = (u16*)d_out;
    u16* xb      = scratch;
    u16* WqkvT   = scratch + (size_t)MROWS * D_;

    const size_t Y1E = (size_t)MROWS * D_;   // y1 elems (== HEADELEMS)
    const size_t WPE = (size_t)D_ * D_;      // WprojT elems

    u16* qkv = (u16*)d_ws;
    u16* Qp  = qkv;
    u16* Kp  = qkv + (size_t)HEADELEMS;
    u16* Vtp = qkv + (size_t)2 * HEADELEMS;

    const bool huge = ws_size >= ((size_t)3 * HEADELEMS + Y1E + WPE) * 2;
    const bool big  = ws_size >= ((size_t)3 * HEADELEMS + Y1E) * 2;

    u16* y1b    = big ? qkv + (size_t)3 * HEADELEMS : scratch;
    u16* y1g    = big ? y1b : Vtp;
    u16* WprojT = huge ? qkv + (size_t)3 * HEADELEMS + Y1E : Kp;

    // 1) fused prep
    prep_kernel<<<huge ? 5120 : 4864, 256, 0, stream>>>(
        x, Wqkv, Wproj, xb, WqkvT, WprojT);

    // 2) QKV GEMM -> Q(prescaled) | K | VT (bf16) in ws; 64x128 tiles,
    //    grid (24, 64) = 1536 blocks -> 6 blocks/CU
    gemm_mfma<1><<<dim3(3*D_/128, MROWS/64), 128, 0, stream>>>(
        xb, WqkvT, bqkv, (void*)qkv, MROWS, 3*D_, D_);

    // 3) attention -> y1 bf16; grid (hb=32, y=32), 64 q-rows/block
    attn_mfma_kernel<<<dim3(NH_*B_, T_/64), 256, 0, stream>>>(Qp, Kp, Vtp, y1b);

    // 4) Wproj transpose (non-huge paths; K dead now)
    if (!huge)
        transpose_conv_kernel<<<dim3(D_/64, D_/64), 256, 0, stream>>>(
            Wproj, WprojT, D_, D_);

    // 5) small-ws fallback: move y1 out of d_out
    if (!big)
        (void)hipMemcpyAsync(y1g, y1b, Y1E * sizeof(u16),
                             hipMemcpyDeviceToDevice, stream);

    // 6) output projection -> fp32 d_out; grid (8, 64) = 512 blocks
    gemm_mfma<0><<<dim3(D_/128, MROWS/64), 128, 0, stream>>>(
        y1g, WprojT, bproj, d_out, MROWS, D_, D_);
}

// Round 4
// 195.979 us; speedup vs baseline: 1.0630x; 1.0630x over previous
//
#include <hip/hip_runtime.h>
#include <hip/hip_bf16.h>

// Problem constants
#define B_   2
#define T_   2048
#define D_   1024
#define NH_  16
#define HD_  64
#define MROWS (B_*T_)              // 4096
#define HEADELEMS (B_*NH_*T_*HD_)  // 4194304 per Q/K/V tensor

// exp(s/8) = 2^(s * 0.125 * log2 e); folded into Q at the QKV epilogue
#define QSCALE 0.180336880f

typedef unsigned short u16;
typedef unsigned int   u32;

typedef float f32x4  __attribute__((ext_vector_type(4)));
typedef short bf16x8 __attribute__((ext_vector_type(8)));

// async global->LDS, 16 B/lane; LDS dest = wave-uniform base + lane*16
#define GLP(g, l) __builtin_amdgcn_global_load_lds(                         \
    (const __attribute__((address_space(1))) void*)(g),                     \
    (__attribute__((address_space(3))) void*)(l), 16, 0, 0)

struct Fc { static constexpr bool value = false; };
struct Tc { static constexpr bool value = true;  };

__device__ __forceinline__ u16 f2bf(float f) {
    u32 x = __float_as_uint(f);
    u32 r = (x + 0x7fffu + ((x >> 16) & 1u)) >> 16;
    return (u16)r;
}
// packed fp32x2 -> bf16x2
__device__ __forceinline__ u32 pkbf2(float a, float b) {
    __hip_bfloat162 h = __float22bfloat162_rn(make_float2(a, b));
    union { __hip_bfloat162 h2; u32 u; } cv; cv.h2 = h; return cv.u;
}

// ---------------------------------------------------------------------------
// Fused prep: [0,4096) x fp32->bf16; [4096,4864) Wqkv -> bf16 T;
// [4864,5120) Wproj -> bf16 T (only launched on the huge-ws path).
// ---------------------------------------------------------------------------
__device__ __forceinline__ void transpose_tile(const float* in, u16* out,
                                               int K, int N, int bx, int by,
                                               int t, float (*Ts)[65])
{
    const int n0 = bx * 64;
    const int k0 = by * 64;
    #pragma unroll
    for (int pass = 0; pass < 4; pass++) {
        const int r = pass * 16 + (t >> 4);
        const int c = (t & 15) * 4;
        float4 v = *(const float4*)(in + (size_t)(k0 + r) * N + n0 + c);
        Ts[r][c] = v.x; Ts[r][c+1] = v.y; Ts[r][c+2] = v.z; Ts[r][c+3] = v.w;
    }
    __syncthreads();
    #pragma unroll
    for (int pass = 0; pass < 2; pass++) {
        const int nn = pass * 32 + (t >> 3);
        const int kk = (t & 7) * 8;
        u16 o[8];
        #pragma unroll
        for (int j = 0; j < 8; j++) o[j] = f2bf(Ts[kk + j][nn]);
        *(uint4*)(out + (size_t)(n0 + nn) * K + k0 + kk) = *(const uint4*)o;
    }
}

__global__ __launch_bounds__(256)
void prep_kernel(const float* __restrict__ x, const float* __restrict__ Wqkv,
                 const float* __restrict__ Wproj, u16* __restrict__ xb,
                 u16* __restrict__ WqkvT, u16* __restrict__ WprojT)
{
    __shared__ float Ts[64][65];
    const int bid = blockIdx.x;
    const int t   = threadIdx.x;
    if (bid < 4096) {
        int i = bid * 256 + t;
        float4 v = ((const float4*)x)[i];
        ushort4 o;
        o.x = f2bf(v.x); o.y = f2bf(v.y); o.z = f2bf(v.z); o.w = f2bf(v.w);
        ((ushort4*)xb)[i] = o;
    } else if (bid < 4096 + 768) {
        int tb = bid - 4096;                   // [3072][1024] T
        transpose_tile(Wqkv, WqkvT, D_, 3*D_, tb % 48, tb / 48, t, Ts);
    } else {
        int tb = bid - 4864;                   // [1024][1024] T
        transpose_tile(Wproj, WprojT, D_, D_, tb % 16, tb / 16, t, Ts);
    }
}

__global__ __launch_bounds__(256)
void transpose_conv_kernel(const float* __restrict__ in, u16* __restrict__ out,
                           int K, int N)
{
    __shared__ float Ts[64][65];
    transpose_tile(in, out, K, N, blockIdx.x, blockIdx.y, threadIdx.x, Ts);
}

// ---------------------------------------------------------------------------
// MFMA GEMM. Round-14: back to the proven 128x128 / 4-wave / 256-thread
// structure (r1 pipeline and r3 small-tile both regressed; residency is
// stuck at ~2-3 blocks/CU regardless of grid), but with BK=64: halves the
// number of barrier/vmcnt(0)-drain windows (16 vs 32) and doubles the MFMA
// work per window (32/wave vs 16). LDS 32 KB (<= 5 blocks/CU cap), same
// 2-barrier schedule the compiler handles well.
// BK=64 makes the row stride 128 B (the classic 32-way-conflict stride),
// so the XOR swizzle is re-derived for 8 segs/row: stored_seg =
// logical_seg ^ (row&7), applied on the pre-swizzled GLOBAL source (GLP's
// LDS dest must stay linear); frag read col = ((quad^(l16&7))*8) ^ (kk*32)
// -> each wave's 64 lanes hit all 32 banks at 2 lanes/bank (free).
// MODE 0: fp32 row-major + bias. MODE 1: scatter bf16 Q(*QSCALE),K | V^T
// (uint2-packed along t).
// ---------------------------------------------------------------------------
template <int MODE>
__global__ __launch_bounds__(256)
void gemm_mfma(const u16* __restrict__ A, const u16* __restrict__ BT,
               const float* __restrict__ bias, void* __restrict__ outv,
               int M, int N, int K)
{
    __shared__ u16 As[128][64];
    __shared__ u16 Bs[128][64];

    const int t    = threadIdx.x;
    const int wave = t >> 6;
    const int lane = t & 63;
    const int l16  = lane & 15;
    const int quad = lane >> 4;

    const int m0 = blockIdx.y * 128;
    const int n0 = blockIdx.x * 128;
    const int mb = (wave >> 1) * 64;
    const int nb = (wave & 1) * 64;

    // BK=64 staging: 8 rows per GLP (8 lanes/row, 16 B each). Global-side
    // XOR seg swizzle: lane covers (row = rw+g*8+srow, stored seg lane&7),
    // whose logical seg is (lane&7)^(row&7) = (lane&7)^srow.
    const int srow = lane >> 3;                  // 0..7
    const int sseg = ((lane & 7) ^ srow) * 8;    // pre-swizzled k-offset

    const int rw = wave * 32;                    // wave's 32-row span
    const u16* gA = A  + (size_t)(m0 + rw + srow) * K + sseg;
    const u16* gB = BT + (size_t)(n0 + rw + srow) * K + sseg;

    // frag read col (elems): logical seg = quad (kk=0) / quad^4 (kk=1);
    // stored at logical ^ (row&7) with row&7 == l16&7.
    const int fragcol = (quad ^ (l16 & 7)) * 8;

    f32x4 acc[4][4];
    #pragma unroll
    for (int i = 0; i < 4; i++)
        #pragma unroll
        for (int j = 0; j < 4; j++) acc[i][j] = (f32x4){0,0,0,0};

    for (int k0 = 0; k0 < K; k0 += 64) {
        __syncthreads();
        GLP(gA + k0,            &As[rw     ][0]);
        GLP(gA + k0 +  8*K,     &As[rw +  8][0]);
        GLP(gA + k0 + 16*K,     &As[rw + 16][0]);
        GLP(gA + k0 + 24*K,     &As[rw + 24][0]);
        GLP(gB + k0,            &Bs[rw     ][0]);
        GLP(gB + k0 +  8*K,     &Bs[rw +  8][0]);
        GLP(gB + k0 + 16*K,     &Bs[rw + 16][0]);
        GLP(gB + k0 + 24*K,     &Bs[rw + 24][0]);
        __syncthreads();

        #pragma unroll
        for (int kk = 0; kk < 2; kk++) {
            const int fc = fragcol ^ (kk << 5);
            bf16x8 af[4], bfr[4];
            #pragma unroll
            for (int i = 0; i < 4; i++)
                af[i] = *(const bf16x8*)&As[mb + i*16 + l16][fc];
            #pragma unroll
            for (int j = 0; j < 4; j++)
                bfr[j] = *(const bf16x8*)&Bs[nb + j*16 + l16][fc];

            #pragma unroll
            for (int i = 0; i < 4; i++)
                #pragma unroll
                for (int j = 0; j < 4; j++)
                    acc[i][j] = __builtin_amdgcn_mfma_f32_16x16x32_bf16(
                        af[i], bfr[j], acc[i][j], 0, 0, 0);
        }
    }

    if (MODE == 0) {
        #pragma unroll
        for (int j = 0; j < 4; j++) {
            const int n = n0 + nb + j*16 + l16;
            const float bv = bias[n];
            #pragma unroll
            for (int i = 0; i < 4; i++) {
                #pragma unroll
                for (int r = 0; r < 4; r++) {
                    const int m = m0 + mb + i*16 + quad*4 + r;
                    ((float*)outv)[(size_t)m * N + n] = acc[i][j][r] + bv;
                }
            }
        }
    } else {
        const int sec = n0 >> 10;        // block-uniform: 0=q 1=k 2=v
        const int b   = m0 >> 11;        // block-uniform batch index
        const int tb  = m0 & 2047;
        if (sec < 2) {
            // Q/K: [b,h,t,hd] layout; hd = l16-contiguous (32B runs)
            const float qs = (sec == 0) ? QSCALE : 1.f;
            #pragma unroll
            for (int j = 0; j < 4; j++) {
                const int n  = n0 + nb + j*16 + l16;
                const float bv = bias[n];
                const int dd = n & 1023;
                const int h  = dd >> 6;
                const int hd = dd & 63;
                u16* op = (u16*)outv + (size_t)sec * HEADELEMS
                        + ((size_t)(b*NH_ + h)) * T_ * HD_ + hd;
                #pragma unroll
                for (int i = 0; i < 4; i++) {
                    #pragma unroll
                    for (int r = 0; r < 4; r++) {
                        const int tt = tb + mb + i*16 + quad*4 + r;
                        op[(size_t)tt * HD_] = f2bf((acc[i][j][r] + bv) * qs);
                    }
                }
            }
        } else {
            // V^T: [b,h,hd,t] layout; 4 consecutive r == consecutive tt ->
            // one 8B store each (16 uint2/thread vs 64 scalar u16)
            #pragma unroll
            for (int j = 0; j < 4; j++) {
                const int n  = n0 + nb + j*16 + l16;
                const float bv = bias[n];
                const int dd = n & 1023;
                const int h  = dd >> 6;
                const int hd = dd & 63;
                u16* vp = (u16*)outv + (size_t)2 * HEADELEMS
                        + ((size_t)(b*NH_ + h)) * T_ * HD_
                        + (size_t)hd * T_ + tb + mb;
                #pragma unroll
                for (int i = 0; i < 4; i++) {
                    u16 o[4];
                    #pragma unroll
                    for (int r = 0; r < 4; r++) o[r] = f2bf(acc[i][j][r] + bv);
                    *(uint2*)(vp + i*16 + quad*4) = *(const uint2*)o;
                }
            }
        }
    }
}

// ---------------------------------------------------------------------------
// MFMA flash attention v6 (causal, no-max softmax; scores bounded ~2.5).
// 64 q-rows/block (16/wave), grid (hb=32, y=32) = 1024 blocks -> 4 blocks/CU
// (LDS 36.9 KB fits exactly 4). Co-resident blocks {yy,yy+8,yy+16,yy+24}
// get qt {31-a,16+a,15-a,a} -> constant 62 tiles/CU. In-register C->A
// shuffle redistribution, ones-MFMA row sums, compile-time masked-tile
// split. T5 s_setprio(1) around the MFMA clusters (blocks on one CU run at
// independent phases -> scheduler favors MFMA-issuing waves; m191 +4-7%).
// ---------------------------------------------------------------------------
__global__ __launch_bounds__(256)
void attn_mfma_kernel(const u16* __restrict__ Q, const u16* __restrict__ K,
                      const u16* __restrict__ VT, u16* __restrict__ y1)
{
    __shared__ u16 Ks[2][64][72];     // [buf][key][d]
    __shared__ u16 Vs[2][64][72];     // [buf][d][key]

    const int t    = threadIdx.x;
    const int wave = t >> 6;
    const int lane = t & 63;
    const int l16  = lane & 15;
    const int quad = lane >> 4;

    const int hb = blockIdx.x;                 // b*NH + h (XCD-pinned)
    const int yy = blockIdx.y;
    const int a  = yy & 7, g = yy >> 3;
    const int qt = (g == 0) ? 31 - a : (g == 1) ? 16 + a
                 : (g == 2) ? 15 - a : a;      // balanced 4-way pairing
    const int b  = hb >> 4;
    const int h  = hb & 15;
    const size_t base = (size_t)hb * T_ * HD_;

    const int qw0 = qt * 64 + wave * 16;       // first q-row of this wave

    // Q fragment: 2 d-chunks (Q pre-scaled by QSCALE)
    bf16x8 qf[2];
    {
        const u16* qp = Q + base + (size_t)(qw0 + l16) * HD_ + quad * 8;
        qf[0] = *(const bf16x8*)(qp);
        qf[1] = *(const bf16x8*)(qp + 32);
    }

    bf16x8 onesf;
    #pragma unroll
    for (int i = 0; i < 8; i++) onesf[i] = (short)0x3F80;

    f32x4 o[4];
    #pragma unroll
    for (int d = 0; d < 4; d++) o[d] = (f32x4){0,0,0,0};
    f32x4 accl = (f32x4){0,0,0,0};

    const int nsteps = qt + 1;                 // uniform across waves;
                                               // fullw = qt, masked = last

    const int srow = t >> 3;
    const int scol = (t & 7) * 8;

    // shuffle sources for C->A redistribution (r10-verified)
    const int srcA  = l16 + ((quad & 1) << 5);
    const int srcB  = srcA + 16;
    const bool selhi = (quad >> 1) != 0;

    // stage tile 0
    uint4 kr0, kr1, vr0, vr1;
    {
        const u16* kp = K + base + (size_t)srow * HD_ + scol;
        kr0 = *(const uint4*)kp;
        kr1 = *(const uint4*)(kp + 32 * HD_);
        const u16* vp = VT + base + (size_t)srow * T_ + scol;
        vr0 = *(const uint4*)vp;
        vr1 = *(const uint4*)(vp + 32 * T_);
        *(uint4*)&Ks[0][srow][scol]      = kr0;
        *(uint4*)&Ks[0][srow + 32][scol] = kr1;
        *(uint4*)&Vs[0][srow][scol]      = vr0;
        *(uint4*)&Vs[0][srow + 32][scol] = vr1;
    }
    __syncthreads();

    auto compute_tile = [&](int cur, int k0, auto mc) {
        constexpr bool MASKED = decltype(mc)::value;
        // S^T = K_tile . Q^T
        f32x4 st[4];
        __builtin_amdgcn_s_setprio(1);
        #pragma unroll
        for (int j = 0; j < 4; j++) {
            bf16x8 kf0 = *(const bf16x8*)&Ks[cur][j*16 + l16][quad * 8];
            bf16x8 kf1 = *(const bf16x8*)&Ks[cur][j*16 + l16][32 + quad * 8];
            f32x4 z = {0,0,0,0};
            z = __builtin_amdgcn_mfma_f32_16x16x32_bf16(kf0, qf[0], z, 0, 0, 0);
            st[j] = __builtin_amdgcn_mfma_f32_16x16x32_bf16(kf1, qf[1], z, 0, 0, 0);
        }
        __builtin_amdgcn_s_setprio(0);

        // exp2 (+ mask, compile-time gated) + packed bf16
        u32 p01[4], p23[4];
        const int qi = qw0 + l16;
        #pragma unroll
        for (int j = 0; j < 4; j++) {
            const int kb = k0 + j*16 + quad*4;
            float e0 = __builtin_amdgcn_exp2f(st[j][0]);
            float e1 = __builtin_amdgcn_exp2f(st[j][1]);
            float e2 = __builtin_amdgcn_exp2f(st[j][2]);
            float e3 = __builtin_amdgcn_exp2f(st[j][3]);
            if (MASKED) {
                if (kb + 0 > qi) e0 = 0.f;
                if (kb + 1 > qi) e1 = 0.f;
                if (kb + 2 > qi) e2 = 0.f;
                if (kb + 3 > qi) e3 = 0.f;
            }
            p01[j] = pkbf2(e0, e1);
            p23[j] = pkbf2(e2, e3);
        }

        // C->A redistribution via shuffles; then ones-MFMA + PV
        bf16x8 pf[2];
        #pragma unroll
        for (int c = 0; c < 2; c++) {
            u32 t0, t1, r01, r23, r45, r67;
            t0 = (u32)__shfl((int)p01[2*c],   srcA);
            t1 = (u32)__shfl((int)p01[2*c+1], srcA);
            r01 = selhi ? t1 : t0;
            t0 = (u32)__shfl((int)p23[2*c],   srcA);
            t1 = (u32)__shfl((int)p23[2*c+1], srcA);
            r23 = selhi ? t1 : t0;
            t0 = (u32)__shfl((int)p01[2*c],   srcB);
            t1 = (u32)__shfl((int)p01[2*c+1], srcB);
            r45 = selhi ? t1 : t0;
            t0 = (u32)__shfl((int)p23[2*c],   srcB);
            t1 = (u32)__shfl((int)p23[2*c+1], srcB);
            r67 = selhi ? t1 : t0;
            union { u32 u[4]; bf16x8 v; } pk;
            pk.u[0] = r01; pk.u[1] = r23; pk.u[2] = r45; pk.u[3] = r67;
            pf[c] = pk.v;
        }
        __builtin_amdgcn_s_setprio(1);
        accl = __builtin_amdgcn_mfma_f32_16x16x32_bf16(pf[0], onesf, accl, 0, 0, 0);
        accl = __builtin_amdgcn_mfma_f32_16x16x32_bf16(pf[1], onesf, accl, 0, 0, 0);
        #pragma unroll
        for (int d = 0; d < 4; d++) {
            bf16x8 v0 = *(const bf16x8*)&Vs[cur][d*16 + l16][quad * 8];
            bf16x8 v1 = *(const bf16x8*)&Vs[cur][d*16 + l16][32 + quad * 8];
            o[d] = __builtin_amdgcn_mfma_f32_16x16x32_bf16(pf[0], v0, o[d], 0, 0, 0);
            o[d] = __builtin_amdgcn_mfma_f32_16x16x32_bf16(pf[1], v1, o[d], 0, 0, 0);
        }
        __builtin_amdgcn_s_setprio(0);
    };

    for (int kt = 0; kt < nsteps; kt++) {
        const int cur = kt & 1;
        const int k0  = kt * 64;
        const bool have_next = (kt + 1 < nsteps);

        if (have_next) {
            const u16* kp = K + base + (size_t)(k0 + 64 + srow) * HD_ + scol;
            kr0 = *(const uint4*)kp;
            kr1 = *(const uint4*)(kp + 32 * HD_);
            const u16* vp = VT + base + (size_t)srow * T_ + k0 + 64 + scol;
            vr0 = *(const uint4*)vp;
            vr1 = *(const uint4*)(vp + 32 * T_);
        }

        if (kt < qt) compute_tile(cur, k0, Fc{});
        else         compute_tile(cur, k0, Tc{});

        if (have_next) {
            const int nxt = cur ^ 1;
            *(uint4*)&Ks[nxt][srow][scol]      = kr0;
            *(uint4*)&Ks[nxt][srow + 32][scol] = kr1;
            *(uint4*)&Vs[nxt][srow][scol]      = vr0;
            *(uint4*)&Vs[nxt][srow + 32][scol] = vr1;
            __syncthreads();
        }
    }

    // epilogue: normalize by ones-MFMA row sums; y1[B,T,D] bf16
    #pragma unroll
    for (int r = 0; r < 4; r++) {
        const float inv = 1.f / accl[r];
        const int qi = qw0 + quad*4 + r;
        u16* yp = y1 + ((size_t)(b * T_ + qi)) * D_ + h * HD_ + l16;
        yp[0]  = f2bf(o[0][r] * inv);
        yp[16] = f2bf(o[1][r] * inv);
        yp[32] = f2bf(o[2][r] * inv);
        yp[48] = f2bf(o[3][r] * inv);
    }
}

// ---------------------------------------------------------------------------
// Choreography, three ws tiers:
//  huge (>= 3*QKV + y1 + WprojT = ~35.7 MB): prep also transposes Wproj into
//    ws; attn -> y1 in ws; 4 dispatches, no memcpy.
//  big  (>= 3*QKV + y1 = ~33.5 MB): y1 in ws; WprojT over dead K after attn.
//  small: y1 over dead xb in d_out; memcpy to dead VT; WprojT over dead K.
// ---------------------------------------------------------------------------
extern "C" void kernel_launch(void* const* d_in, const int* in_sizes, int n_in,
                              void* d_out, int out_size, void* d_ws, size_t ws_size,
                              hipStream_t stream)
{
    const float* x     = (const float*)d_in[0];
    const float* Wqkv  = (const float*)d_in[1];
    const float* bqkv  = (const float*)d_in[2];
    const float* Wproj = (const float*)d_in[3];
    const float* bproj = (const float*)d_in[4];

    u16* scratch = (u16*)d_out;
    u16* xb      = scratch;
    u16* WqkvT   = scratch + (size_t)MROWS * D_;

    const size_t Y1E = (size_t)MROWS * D_;   // y1 elems (== HEADELEMS)
    const size_t WPE = (size_t)D_ * D_;      // WprojT elems

    u16* qkv = (u16*)d_ws;
    u16* Qp  = qkv;
    u16* Kp  = qkv + (size_t)HEADELEMS;
    u16* Vtp = qkv + (size_t)2 * HEADELEMS;

    const bool huge = ws_size >= ((size_t)3 * HEADELEMS + Y1E + WPE) * 2;
    const bool big  = ws_size >= ((size_t)3 * HEADELEMS + Y1E) * 2;

    u16* y1b    = big ? qkv + (size_t)3 * HEADELEMS : scratch;
    u16* y1g    = big ? y1b : Vtp;
    u16* WprojT = huge ? qkv + (size_t)3 * HEADELEMS + Y1E : Kp;

    // 1) fused prep
    prep_kernel<<<huge ? 5120 : 4864, 256, 0, stream>>>(
        x, Wqkv, Wproj, xb, WqkvT, WprojT);

    // 2) QKV GEMM -> Q(prescaled) | K | VT (bf16) in ws; 128x128 tiles
    gemm_mfma<1><<<dim3(3*D_/128, MROWS/128), 256, 0, stream>>>(
        xb, WqkvT, bqkv, (void*)qkv, MROWS, 3*D_, D_);

    // 3) attention -> y1 bf16; grid (hb=32, y=32), 64 q-rows/block
    attn_mfma_kernel<<<dim3(NH_*B_, T_/64), 256, 0, stream>>>(Qp, Kp, Vtp, y1b);

    // 4) Wproj transpose (non-huge paths; K dead now)
    if (!huge)
        transpose_conv_kernel<<<dim3(D_/64, D_/64), 256, 0, stream>>>(
            Wproj, WprojT, D_, D_);

    // 5) small-ws fallback: move y1 out of d_out
    if (!big)
        (void)hipMemcpyAsync(y1g, y1b, Y1E * sizeof(u16),
                             hipMemcpyDeviceToDevice, stream);

    // 6) output projection -> fp32 d_out
    gemm_mfma<0><<<dim3(D_/128, MROWS/128), 256, 0, stream>>>(
        y1g, WprojT, bproj, d_out, MROWS, D_, D_);
}

// Round 7
// 195.173 us; speedup vs baseline: 1.0674x; 1.0041x over previous
//
#include <hip/hip_runtime.h>
#include <hip/hip_bf16.h>

// Problem constants
#define B_   2
#define T_   2048
#define D_   1024
#define NH_  16
#define HD_  64
#define MROWS (B_*T_)              // 4096
#define HEADELEMS (B_*NH_*T_*HD_)  // 4194304 per Q/K/V tensor

// exp(s/8) = 2^(s * 0.125 * log2 e); folded into Q at the QKV epilogue
#define QSCALE 0.180336880f

typedef unsigned short u16;
typedef unsigned int   u32;

typedef float f32x4  __attribute__((ext_vector_type(4)));
typedef short bf16x8 __attribute__((ext_vector_type(8)));

// async global->LDS, 16 B/lane; LDS dest = wave-uniform base + lane*16
#define GLP(g, l) __builtin_amdgcn_global_load_lds(                         \
    (const __attribute__((address_space(1))) void*)(g),                     \
    (__attribute__((address_space(3))) void*)(l), 16, 0, 0)

struct Fc { static constexpr bool value = false; };
struct Tc { static constexpr bool value = true;  };

__device__ __forceinline__ u16 f2bf(float f) {
    u32 x = __float_as_uint(f);
    u32 r = (x + 0x7fffu + ((x >> 16) & 1u)) >> 16;
    return (u16)r;
}
// packed fp32x2 -> bf16x2
__device__ __forceinline__ u32 pkbf2(float a, float b) {
    __hip_bfloat162 h = __float22bfloat162_rn(make_float2(a, b));
    union { __hip_bfloat162 h2; u32 u; } cv; cv.h2 = h; return cv.u;
}

// ---------------------------------------------------------------------------
// Fused prep: [0,4096) x fp32->bf16; [4096,4864) Wqkv -> bf16 T;
// [4864,5120) Wproj -> bf16 T (only launched on the huge-ws path).
// ---------------------------------------------------------------------------
__device__ __forceinline__ void transpose_tile(const float* in, u16* out,
                                               int K, int N, int bx, int by,
                                               int t, float (*Ts)[65])
{
    const int n0 = bx * 64;
    const int k0 = by * 64;
    #pragma unroll
    for (int pass = 0; pass < 4; pass++) {
        const int r = pass * 16 + (t >> 4);
        const int c = (t & 15) * 4;
        float4 v = *(const float4*)(in + (size_t)(k0 + r) * N + n0 + c);
        Ts[r][c] = v.x; Ts[r][c+1] = v.y; Ts[r][c+2] = v.z; Ts[r][c+3] = v.w;
    }
    __syncthreads();
    #pragma unroll
    for (int pass = 0; pass < 2; pass++) {
        const int nn = pass * 32 + (t >> 3);
        const int kk = (t & 7) * 8;
        u16 o[8];
        #pragma unroll
        for (int j = 0; j < 8; j++) o[j] = f2bf(Ts[kk + j][nn]);
        *(uint4*)(out + (size_t)(n0 + nn) * K + k0 + kk) = *(const uint4*)o;
    }
}

__global__ __launch_bounds__(256)
void prep_kernel(const float* __restrict__ x, const float* __restrict__ Wqkv,
                 const float* __restrict__ Wproj, u16* __restrict__ xb,
                 u16* __restrict__ WqkvT, u16* __restrict__ WprojT)
{
    __shared__ float Ts[64][65];
    const int bid = blockIdx.x;
    const int t   = threadIdx.x;
    if (bid < 4096) {
        int i = bid * 256 + t;
        float4 v = ((const float4*)x)[i];
        ushort4 o;
        o.x = f2bf(v.x); o.y = f2bf(v.y); o.z = f2bf(v.z); o.w = f2bf(v.w);
        ((ushort4*)xb)[i] = o;
    } else if (bid < 4096 + 768) {
        int tb = bid - 4096;                   // [3072][1024] T
        transpose_tile(Wqkv, WqkvT, D_, 3*D_, tb % 48, tb / 48, t, Ts);
    } else {
        int tb = bid - 4864;                   // [1024][1024] T
        transpose_tile(Wproj, WprojT, D_, D_, tb % 16, tb / 16, t, Ts);
    }
}

__global__ __launch_bounds__(256)
void transpose_conv_kernel(const float* __restrict__ in, u16* __restrict__ out,
                           int K, int N)
{
    __shared__ float Ts[64][65];
    transpose_tile(in, out, K, N, blockIdx.x, blockIdx.y, threadIdx.x, Ts);
}

// ---------------------------------------------------------------------------
// MFMA GEMM (r4 config, kept: 49.4 µs, slightly better than BK=32's 50.1):
// 128x128 / 4-wave / BK=64, global-side XOR seg swizzle (8 segs/row),
// frag read col = ((quad^(l16&7))*8) ^ (kk*32).
// MODE 0: fp32 row-major + bias. MODE 1: scatter bf16 Q(*QSCALE),K | V^T
// (uint2-packed along t).
// ---------------------------------------------------------------------------
template <int MODE>
__global__ __launch_bounds__(256)
void gemm_mfma(const u16* __restrict__ A, const u16* __restrict__ BT,
               const float* __restrict__ bias, void* __restrict__ outv,
               int M, int N, int K)
{
    __shared__ u16 As[128][64];
    __shared__ u16 Bs[128][64];

    const int t    = threadIdx.x;
    const int wave = t >> 6;
    const int lane = t & 63;
    const int l16  = lane & 15;
    const int quad = lane >> 4;

    const int m0 = blockIdx.y * 128;
    const int n0 = blockIdx.x * 128;
    const int mb = (wave >> 1) * 64;
    const int nb = (wave & 1) * 64;

    const int srow = lane >> 3;                  // 0..7
    const int sseg = ((lane & 7) ^ srow) * 8;    // pre-swizzled k-offset

    const int rw = wave * 32;                    // wave's 32-row span
    const u16* gA = A  + (size_t)(m0 + rw + srow) * K + sseg;
    const u16* gB = BT + (size_t)(n0 + rw + srow) * K + sseg;

    const int fragcol = (quad ^ (l16 & 7)) * 8;

    f32x4 acc[4][4];
    #pragma unroll
    for (int i = 0; i < 4; i++)
        #pragma unroll
        for (int j = 0; j < 4; j++) acc[i][j] = (f32x4){0,0,0,0};

    for (int k0 = 0; k0 < K; k0 += 64) {
        __syncthreads();
        GLP(gA + k0,            &As[rw     ][0]);
        GLP(gA + k0 +  8*K,     &As[rw +  8][0]);
        GLP(gA + k0 + 16*K,     &As[rw + 16][0]);
        GLP(gA + k0 + 24*K,     &As[rw + 24][0]);
        GLP(gB + k0,            &Bs[rw     ][0]);
        GLP(gB + k0 +  8*K,     &Bs[rw +  8][0]);
        GLP(gB + k0 + 16*K,     &Bs[rw + 16][0]);
        GLP(gB + k0 + 24*K,     &Bs[rw + 24][0]);
        __syncthreads();

        #pragma unroll
        for (int kk = 0; kk < 2; kk++) {
            const int fc = fragcol ^ (kk << 5);
            bf16x8 af[4], bfr[4];
            #pragma unroll
            for (int i = 0; i < 4; i++)
                af[i] = *(const bf16x8*)&As[mb + i*16 + l16][fc];
            #pragma unroll
            for (int j = 0; j < 4; j++)
                bfr[j] = *(const bf16x8*)&Bs[nb + j*16 + l16][fc];

            #pragma unroll
            for (int i = 0; i < 4; i++)
                #pragma unroll
                for (int j = 0; j < 4; j++)
                    acc[i][j] = __builtin_amdgcn_mfma_f32_16x16x32_bf16(
                        af[i], bfr[j], acc[i][j], 0, 0, 0);
        }
    }

    if (MODE == 0) {
        #pragma unroll
        for (int j = 0; j < 4; j++) {
            const int n = n0 + nb + j*16 + l16;
            const float bv = bias[n];
            #pragma unroll
            for (int i = 0; i < 4; i++) {
                #pragma unroll
                for (int r = 0; r < 4; r++) {
                    const int m = m0 + mb + i*16 + quad*4 + r;
                    ((float*)outv)[(size_t)m * N + n] = acc[i][j][r] + bv;
                }
            }
        }
    } else {
        const int sec = n0 >> 10;        // block-uniform: 0=q 1=k 2=v
        const int b   = m0 >> 11;        // block-uniform batch index
        const int tb  = m0 & 2047;
        if (sec < 2) {
            // Q/K: [b,h,t,hd] layout; hd = l16-contiguous (32B runs)
            const float qs = (sec == 0) ? QSCALE : 1.f;
            #pragma unroll
            for (int j = 0; j < 4; j++) {
                const int n  = n0 + nb + j*16 + l16;
                const float bv = bias[n];
                const int dd = n & 1023;
                const int h  = dd >> 6;
                const int hd = dd & 63;
                u16* op = (u16*)outv + (size_t)sec * HEADELEMS
                        + ((size_t)(b*NH_ + h)) * T_ * HD_ + hd;
                #pragma unroll
                for (int i = 0; i < 4; i++) {
                    #pragma unroll
                    for (int r = 0; r < 4; r++) {
                        const int tt = tb + mb + i*16 + quad*4 + r;
                        op[(size_t)tt * HD_] = f2bf((acc[i][j][r] + bv) * qs);
                    }
                }
            }
        } else {
            // V^T: [b,h,hd,t] layout; 4 consecutive r == consecutive tt ->
            // one 8B store each
            #pragma unroll
            for (int j = 0; j < 4; j++) {
                const int n  = n0 + nb + j*16 + l16;
                const float bv = bias[n];
                const int dd = n & 1023;
                const int h  = dd >> 6;
                const int hd = dd & 63;
                u16* vp = (u16*)outv + (size_t)2 * HEADELEMS
                        + ((size_t)(b*NH_ + h)) * T_ * HD_
                        + (size_t)hd * T_ + tb + mb;
                #pragma unroll
                for (int i = 0; i < 4; i++) {
                    u16 o[4];
                    #pragma unroll
                    for (int r = 0; r < 4; r++) o[r] = f2bf(acc[i][j][r] + bv);
                    *(uint2*)(vp + i*16 + quad*4) = *(const uint2*)o;
                }
            }
        }
    }
}

// ---------------------------------------------------------------------------
// MFMA flash attention v7. Round-15 change: LDS BANK-CONFLICT FIX (T2).
// r4 profile: 6.49M SQ_LDS_BANK_CONFLICT/dispatch (~20% of kernel time).
// Old [64][72] layout (144B stride): bank base = 4*(l16+quad) mod 32 ->
// 8 lanes per 4-bank group on every ds_read_b128 AND ds_write_b128.
// New [64][64] layout (128B stride, rows bank-aligned) + XOR seg swizzle,
// both sides (reg->LDS staging, so both are free): stored 16B seg =
// logical_seg ^ (row&7).
//   writes: 8 lanes/row have distinct segs -> 32 banks per 8 lanes, free.
//   reads:  lane(l16,quad) seg = quad^(l16&7); per quad l16 covers all 8
//           segs twice -> 2 lanes/bank (free). kf1/v1 = same addr ^ 64B.
// LDS 36.9 -> 32 KB. Everything else (grid, qt pairing, shuffles, setprio)
// unchanged.
// ---------------------------------------------------------------------------
__global__ __launch_bounds__(256)
void attn_mfma_kernel(const u16* __restrict__ Q, const u16* __restrict__ K,
                      const u16* __restrict__ VT, u16* __restrict__ y1)
{
    __shared__ u16 Ks[2][64][64];     // [buf][key][d]   (XOR-seg swizzled)
    __shared__ u16 Vs[2][64][64];     // [buf][d][key]   (XOR-seg swizzled)

    const int t    = threadIdx.x;
    const int wave = t >> 6;
    const int lane = t & 63;
    const int l16  = lane & 15;
    const int quad = lane >> 4;

    const int hb = blockIdx.x;                 // b*NH + h (XCD-pinned)
    const int yy = blockIdx.y;
    const int a  = yy & 7, g = yy >> 3;
    const int qt = (g == 0) ? 31 - a : (g == 1) ? 16 + a
                 : (g == 2) ? 15 - a : a;      // balanced 4-way pairing
    const int b  = hb >> 4;
    const int h  = hb & 15;
    const size_t base = (size_t)hb * T_ * HD_;

    const int qw0 = qt * 64 + wave * 16;       // first q-row of this wave

    // Q fragment: 2 d-chunks (Q pre-scaled by QSCALE)
    bf16x8 qf[2];
    {
        const u16* qp = Q + base + (size_t)(qw0 + l16) * HD_ + quad * 8;
        qf[0] = *(const bf16x8*)(qp);
        qf[1] = *(const bf16x8*)(qp + 32);
    }

    bf16x8 onesf;
    #pragma unroll
    for (int i = 0; i < 8; i++) onesf[i] = (short)0x3F80;

    f32x4 o[4];
    #pragma unroll
    for (int d = 0; d < 4; d++) o[d] = (f32x4){0,0,0,0};
    f32x4 accl = (f32x4){0,0,0,0};

    const int nsteps = qt + 1;                 // uniform across waves

    const int srow = t >> 3;                   // 0..31
    const int scol = (t & 7) * 8;              // logical seg * 8
    const int sst  = (((t & 7) ^ (srow & 7)) * 8);  // stored (swizzled) col

    // fragment-read swizzled columns: logical seg {quad, quad+4} at row
    // with row&7 == l16&7  ->  stored cols fs0, fs0^32
    const int fs0 = (quad ^ (l16 & 7)) * 8;
    const int fs1 = fs0 ^ 32;

    // shuffle sources for C->A redistribution (r10-verified)
    const int srcA  = l16 + ((quad & 1) << 5);
    const int srcB  = srcA + 16;
    const bool selhi = (quad >> 1) != 0;

    // stage tile 0
    uint4 kr0, kr1, vr0, vr1;
    {
        const u16* kp = K + base + (size_t)srow * HD_ + scol;
        kr0 = *(const uint4*)kp;
        kr1 = *(const uint4*)(kp + 32 * HD_);
        const u16* vp = VT + base + (size_t)srow * T_ + scol;
        vr0 = *(const uint4*)vp;
        vr1 = *(const uint4*)(vp + 32 * T_);
        *(uint4*)&Ks[0][srow][sst]      = kr0;
        *(uint4*)&Ks[0][srow + 32][sst] = kr1;
        *(uint4*)&Vs[0][srow][sst]      = vr0;
        *(uint4*)&Vs[0][srow + 32][sst] = vr1;
    }
    __syncthreads();

    auto compute_tile = [&](int cur, int k0, auto mc) {
        constexpr bool MASKED = decltype(mc)::value;
        // S^T = K_tile . Q^T
        f32x4 st[4];
        __builtin_amdgcn_s_setprio(1);
        #pragma unroll
        for (int j = 0; j < 4; j++) {
            bf16x8 kf0 = *(const bf16x8*)&Ks[cur][j*16 + l16][fs0];
            bf16x8 kf1 = *(const bf16x8*)&Ks[cur][j*16 + l16][fs1];
            f32x4 z = {0,0,0,0};
            z = __builtin_amdgcn_mfma_f32_16x16x32_bf16(kf0, qf[0], z, 0, 0, 0);
            st[j] = __builtin_amdgcn_mfma_f32_16x16x32_bf16(kf1, qf[1], z, 0, 0, 0);
        }
        __builtin_amdgcn_s_setprio(0);

        // exp2 (+ mask, compile-time gated) + packed bf16
        u32 p01[4], p23[4];
        const int qi = qw0 + l16;
        #pragma unroll
        for (int j = 0; j < 4; j++) {
            const int kb = k0 + j*16 + quad*4;
            float e0 = __builtin_amdgcn_exp2f(st[j][0]);
            float e1 = __builtin_amdgcn_exp2f(st[j][1]);
            float e2 = __builtin_amdgcn_exp2f(st[j][2]);
            float e3 = __builtin_amdgcn_exp2f(st[j][3]);
            if (MASKED) {
                if (kb + 0 > qi) e0 = 0.f;
                if (kb + 1 > qi) e1 = 0.f;
                if (kb + 2 > qi) e2 = 0.f;
                if (kb + 3 > qi) e3 = 0.f;
            }
            p01[j] = pkbf2(e0, e1);
            p23[j] = pkbf2(e2, e3);
        }

        // C->A redistribution via shuffles; then ones-MFMA + PV
        bf16x8 pf[2];
        #pragma unroll
        for (int c = 0; c < 2; c++) {
            u32 t0, t1, r01, r23, r45, r67;
            t0 = (u32)__shfl((int)p01[2*c],   srcA);
            t1 = (u32)__shfl((int)p01[2*c+1], srcA);
            r01 = selhi ? t1 : t0;
            t0 = (u32)__shfl((int)p23[2*c],   srcA);
            t1 = (u32)__shfl((int)p23[2*c+1], srcA);
            r23 = selhi ? t1 : t0;
            t0 = (u32)__shfl((int)p01[2*c],   srcB);
            t1 = (u32)__shfl((int)p01[2*c+1], srcB);
            r45 = selhi ? t1 : t0;
            t0 = (u32)__shfl((int)p23[2*c],   srcB);
            t1 = (u32)__shfl((int)p23[2*c+1], srcB);
            r67 = selhi ? t1 : t0;
            union { u32 u[4]; bf16x8 v; } pk;
            pk.u[0] = r01; pk.u[1] = r23; pk.u[2] = r45; pk.u[3] = r67;
            pf[c] = pk.v;
        }
        __builtin_amdgcn_s_setprio(1);
        accl = __builtin_amdgcn_mfma_f32_16x16x32_bf16(pf[0], onesf, accl, 0, 0, 0);
        accl = __builtin_amdgcn_mfma_f32_16x16x32_bf16(pf[1], onesf, accl, 0, 0, 0);
        #pragma unroll
        for (int d = 0; d < 4; d++) {
            bf16x8 v0 = *(const bf16x8*)&Vs[cur][d*16 + l16][fs0];
            bf16x8 v1 = *(const bf16x8*)&Vs[cur][d*16 + l16][fs1];
            o[d] = __builtin_amdgcn_mfma_f32_16x16x32_bf16(pf[0], v0, o[d], 0, 0, 0);
            o[d] = __builtin_amdgcn_mfma_f32_16x16x32_bf16(pf[1], v1, o[d], 0, 0, 0);
        }
        __builtin_amdgcn_s_setprio(0);
    };

    for (int kt = 0; kt < nsteps; kt++) {
        const int cur = kt & 1;
        const int k0  = kt * 64;
        const bool have_next = (kt + 1 < nsteps);

        if (have_next) {
            const u16* kp = K + base + (size_t)(k0 + 64 + srow) * HD_ + scol;
            kr0 = *(const uint4*)kp;
            kr1 = *(const uint4*)(kp + 32 * HD_);
            const u16* vp = VT + base + (size_t)srow * T_ + k0 + 64 + scol;
            vr0 = *(const uint4*)vp;
            vr1 = *(const uint4*)(vp + 32 * T_);
        }

        if (kt < qt) compute_tile(cur, k0, Fc{});
        else         compute_tile(cur, k0, Tc{});

        if (have_next) {
            const int nxt = cur ^ 1;
            *(uint4*)&Ks[nxt][srow][sst]      = kr0;
            *(uint4*)&Ks[nxt][srow + 32][sst] = kr1;
            *(uint4*)&Vs[nxt][srow][sst]      = vr0;
            *(uint4*)&Vs[nxt][srow + 32][sst] = vr1;
            __syncthreads();
        }
    }

    // epilogue: normalize by ones-MFMA row sums; y1[B,T,D] bf16
    #pragma unroll
    for (int r = 0; r < 4; r++) {
        const float inv = 1.f / accl[r];
        const int qi = qw0 + quad*4 + r;
        u16* yp = y1 + ((size_t)(b * T_ + qi)) * D_ + h * HD_ + l16;
        yp[0]  = f2bf(o[0][r] * inv);
        yp[16] = f2bf(o[1][r] * inv);
        yp[32] = f2bf(o[2][r] * inv);
        yp[48] = f2bf(o[3][r] * inv);
    }
}

// ---------------------------------------------------------------------------
// Choreography, three ws tiers:
//  huge (>= 3*QKV + y1 + WprojT = ~35.7 MB): prep also transposes Wproj into
//    ws; attn -> y1 in ws; 4 dispatches, no memcpy.
//  big  (>= 3*QKV + y1 = ~33.5 MB): y1 in ws; WprojT over dead K after attn.
//  small: y1 over dead xb in d_out; memcpy to dead VT; WprojT over dead K.
// ---------------------------------------------------------------------------
extern "C" void kernel_launch(void* const* d_in, const int* in_sizes, int n_in,
                              void* d_out, int out_size, void* d_ws, size_t ws_size,
                              hipStream_t stream)
{
    const float* x     = (const float*)d_in[0];
    const float* Wqkv  = (const float*)d_in[1];
    const float* bqkv  = (const float*)d_in[2];
    const float* Wproj = (const float*)d_in[3];
    const float* bproj = (const float*)d_in[4];

    u16* scratch = (u16*)d_out;
    u16* xb      = scratch;
    u16* WqkvT   = scratch + (size_t)MROWS * D_;

    const size_t Y1E = (size_t)MROWS * D_;   // y1 elems (== HEADELEMS)
    const size_t WPE = (size_t)D_ * D_;      // WprojT elems

    u16* qkv = (u16*)d_ws;
    u16* Qp  = qkv;
    u16* Kp  = qkv + (size_t)HEADELEMS;
    u16* Vtp = qkv + (size_t)2 * HEADELEMS;

    const bool huge = ws_size >= ((size_t)3 * HEADELEMS + Y1E + WPE) * 2;
    const bool big  = ws_size >= ((size_t)3 * HEADELEMS + Y1E) * 2;

    u16* y1b    = big ? qkv + (size_t)3 * HEADELEMS : scratch;
    u16* y1g    = big ? y1b : Vtp;
    u16* WprojT = huge ? qkv + (size_t)3 * HEADELEMS + Y1E : Kp;

    // 1) fused prep
    prep_kernel<<<huge ? 5120 : 4864, 256, 0, stream>>>(
        x, Wqkv, Wproj, xb, WqkvT, WprojT);

    // 2) QKV GEMM -> Q(prescaled) | K | VT (bf16) in ws; 128x128 tiles
    gemm_mfma<1><<<dim3(3*D_/128, MROWS/128), 256, 0, stream>>>(
        xb, WqkvT, bqkv, (void*)qkv, MROWS, 3*D_, D_);

    // 3) attention -> y1 bf16; grid (hb=32, y=32), 64 q-rows/block
    attn_mfma_kernel<<<dim3(NH_*B_, T_/64), 256, 0, stream>>>(Qp, Kp, Vtp, y1b);

    // 4) Wproj transpose (non-huge paths; K dead now)
    if (!huge)
        transpose_conv_kernel<<<dim3(D_/64, D_/64), 256, 0, stream>>>(
            Wproj, WprojT, D_, D_);

    // 5) small-ws fallback: move y1 out of d_out
    if (!big)
        (void)hipMemcpyAsync(y1g, y1b, Y1E * sizeof(u16),
                             hipMemcpyDeviceToDevice, stream);

    // 6) output projection -> fp32 d_out
    gemm_mfma<0><<<dim3(D_/128, MROWS/128), 256, 0, stream>>>(
        y1g, WprojT, bproj, d_out, MROWS, D_, D_);
}

// Round 9
// 194.487 us; speedup vs baseline: 1.0712x; 1.0035x over previous
//
#include <hip/hip_runtime.h>
#include <hip/hip_bf16.h>

// Problem constants
#define B_   2
#define T_   2048
#define D_   1024
#define NH_  16
#define HD_  64
#define MROWS (B_*T_)              // 4096
#define HEADELEMS (B_*NH_*T_*HD_)  // 4194304 per Q/K/V tensor

// exp(s/8) = 2^(s * 0.125 * log2 e); folded into Q at the QKV epilogue
#define QSCALE 0.180336880f

typedef unsigned short u16;
typedef unsigned int   u32;

typedef float f32x4  __attribute__((ext_vector_type(4)));
typedef short bf16x8 __attribute__((ext_vector_type(8)));

// async global->LDS, 16 B/lane; LDS dest MUST be wave-uniform (base+lane*16)
#define GLP(g, l) __builtin_amdgcn_global_load_lds(                         \
    (const __attribute__((address_space(1))) void*)(g),                     \
    (__attribute__((address_space(3))) void*)(l), 16, 0, 0)

struct Fc { static constexpr bool value = false; };
struct Tc { static constexpr bool value = true;  };

__device__ __forceinline__ u16 f2bf(float f) {
    u32 x = __float_as_uint(f);
    u32 r = (x + 0x7fffu + ((x >> 16) & 1u)) >> 16;
    return (u16)r;
}
// packed fp32x2 -> bf16x2
__device__ __forceinline__ u32 pkbf2(float a, float b) {
    __hip_bfloat162 h = __float22bfloat162_rn(make_float2(a, b));
    union { __hip_bfloat162 h2; u32 u; } cv; cv.h2 = h; return cv.u;
}

// ---------------------------------------------------------------------------
// Fused prep: [0,4096) x fp32->bf16; [4096,4864) Wqkv -> bf16 T;
// [4864,5120) Wproj -> bf16 T (only launched on the huge-ws path).
// ---------------------------------------------------------------------------
__device__ __forceinline__ void transpose_tile(const float* in, u16* out,
                                               int K, int N, int bx, int by,
                                               int t, float (*Ts)[65])
{
    const int n0 = bx * 64;
    const int k0 = by * 64;
    #pragma unroll
    for (int pass = 0; pass < 4; pass++) {
        const int r = pass * 16 + (t >> 4);
        const int c = (t & 15) * 4;
        float4 v = *(const float4*)(in + (size_t)(k0 + r) * N + n0 + c);
        Ts[r][c] = v.x; Ts[r][c+1] = v.y; Ts[r][c+2] = v.z; Ts[r][c+3] = v.w;
    }
    __syncthreads();
    #pragma unroll
    for (int pass = 0; pass < 2; pass++) {
        const int nn = pass * 32 + (t >> 3);
        const int kk = (t & 7) * 8;
        u16 o[8];
        #pragma unroll
        for (int j = 0; j < 8; j++) o[j] = f2bf(Ts[kk + j][nn]);
        *(uint4*)(out + (size_t)(n0 + nn) * K + k0 + kk) = *(const uint4*)o;
    }
}

__global__ __launch_bounds__(256)
void prep_kernel(const float* __restrict__ x, const float* __restrict__ Wqkv,
                 const float* __restrict__ Wproj, u16* __restrict__ xb,
                 u16* __restrict__ WqkvT, u16* __restrict__ WprojT)
{
    __shared__ float Ts[64][65];
    const int bid = blockIdx.x;
    const int t   = threadIdx.x;
    if (bid < 4096) {
        int i = bid * 256 + t;
        float4 v = ((const float4*)x)[i];
        ushort4 o;
        o.x = f2bf(v.x); o.y = f2bf(v.y); o.z = f2bf(v.z); o.w = f2bf(v.w);
        ((ushort4*)xb)[i] = o;
    } else if (bid < 4096 + 768) {
        int tb = bid - 4096;                   // [3072][1024] T
        transpose_tile(Wqkv, WqkvT, D_, 3*D_, tb % 48, tb / 48, t, Ts);
    } else {
        int tb = bid - 4864;                   // [1024][1024] T
        transpose_tile(Wproj, WprojT, D_, D_, tb % 16, tb / 16, t, Ts);
    }
}

__global__ __launch_bounds__(256)
void transpose_conv_kernel(const float* __restrict__ in, u16* __restrict__ out,
                           int K, int N)
{
    __shared__ float Ts[64][65];
    transpose_tile(in, out, K, N, blockIdx.x, blockIdx.y, threadIdx.x, Ts);
}

// ---------------------------------------------------------------------------
// MFMA GEMM, round-17: r8's counted-vmcnt pipeline (T4) with the DIVERGENT
// LDS POINTER BUG FIXED. global_load_lds LDS dest must be wave-uniform;
// r8 passed &As[buf][t>>3][0] (per-lane). Now: base = &As[buf][wave*8 +
// {0,32,64,96}][0]; HW writes base + lane*16 -> wave w covers rows
// w*8+(lane>>3), col (lane&7)*16B, matching the per-lane global source
// (row m0+srow, pre-swizzled seg ((t&7)^(srow&7))*8). Stored seg s at row
// r holds logical s^(r&7); frag read col (quad^(l16&7))*8 ^ (kk*32).
// Pipeline per K-step: STAGE(buf^1, k+1) -> vmcnt(8) (tile k's loads only;
// the 8 new stay in flight across the barrier — never drain 0 in-loop) ->
// s_barrier -> ds_read + 32 MFMA -> lgkmcnt(0) + s_barrier (this wave's
// LDS reads complete before any wave's next STAGE overwrites buf).
// 1D launch + bijective XCD swizzle (nwg%8==0): B-panels L2-resident/XCD.
// MODE 0: fp32 row-major + bias. MODE 1: scatter bf16 Q(*QSCALE),K | V^T.
// ---------------------------------------------------------------------------
template <int MODE>
__global__ __launch_bounds__(256)
void gemm_mfma(const u16* __restrict__ A, const u16* __restrict__ BT,
               const float* __restrict__ bias, void* __restrict__ outv,
               int M, int N, int K)
{
    __shared__ u16 As[2][128][64];
    __shared__ u16 Bs[2][128][64];

    const int t    = threadIdx.x;
    const int wave = t >> 6;
    const int lane = t & 63;
    const int l16  = lane & 15;
    const int quad = lane >> 4;

    // bijective XCD swizzle: flat -> (xcd, pos); chunk = (nwg/8) blocks,
    // n-panel-major (bx = idp>>5, by = idp&31; M/128 == 32 for both GEMMs)
    const int flat = blockIdx.x;
    const int cpx  = gridDim.x >> 3;
    const int idp  = (flat & 7) * cpx + (flat >> 3);
    const int bx   = idp >> 5;
    const int by   = idp & 31;

    const int m0 = by * 128;
    const int n0 = bx * 128;
    const int mb = (wave >> 1) * 64;
    const int nb = (wave & 1) * 64;

    // staging: per-lane GLOBAL address (row srow, pre-swizzled seg);
    // wave-uniform LDS base rw8 (+32/64/96)
    const int srow = t >> 3;                     // 0..31 (block-wide)
    const int sseg = ((t & 7) ^ (srow & 7)) * 8; // pre-swizzled k-offset
    const int rw8  = wave * 8;                   // wave-uniform LDS row base

    const u16* gA = A  + (size_t)(m0 + srow) * K + sseg;
    const u16* gB = BT + (size_t)(n0 + srow) * K + sseg;

    // frag read col: logical chunk quad (kk=0) / quad+4 (kk=1), row&7==l16&7
    const int fragcol = (quad ^ (l16 & 7)) * 8;

    f32x4 acc[4][4];
    #pragma unroll
    for (int i = 0; i < 4; i++)
        #pragma unroll
        for (int j = 0; j < 4; j++) acc[i][j] = (f32x4){0,0,0,0};

    // one tile = 8 GLPs (A 4x32 rows, B 4x32 rows); each GLP: 64 lanes x
    // 16B = rows [base, base+8) of 128B
    auto STAGE = [&](int buf, int k0) {
        GLP(gA + k0,          &As[buf][rw8     ][0]);
        GLP(gA + k0 + 32*K,   &As[buf][rw8 + 32][0]);
        GLP(gA + k0 + 64*K,   &As[buf][rw8 + 64][0]);
        GLP(gA + k0 + 96*K,   &As[buf][rw8 + 96][0]);
        GLP(gB + k0,          &Bs[buf][rw8     ][0]);
        GLP(gB + k0 + 32*K,   &Bs[buf][rw8 + 32][0]);
        GLP(gB + k0 + 64*K,   &Bs[buf][rw8 + 64][0]);
        GLP(gB + k0 + 96*K,   &Bs[buf][rw8 + 96][0]);
    };

    const int nk = K >> 6;

    // prologue: tile 0 -> buf 0, full drain once
    STAGE(0, 0);
    asm volatile("s_waitcnt vmcnt(0)" ::: "memory");
    __builtin_amdgcn_s_barrier();

    for (int kt = 0; kt < nk; ++kt) {
        const int cur = kt & 1;
        const bool have_next = (kt + 1 < nk);

        if (have_next) {
            STAGE(cur ^ 1, (kt + 1) << 6);
            // wait ONLY tile kt's 8 loads; the 8 just-issued stay in flight
            asm volatile("s_waitcnt vmcnt(8)" ::: "memory");
        } else {
            asm volatile("s_waitcnt vmcnt(0)" ::: "memory");
        }
        __builtin_amdgcn_s_barrier();

        #pragma unroll
        for (int kk = 0; kk < 2; kk++) {
            const int fc = fragcol ^ (kk << 5);
            bf16x8 af[4], bfr[4];
            #pragma unroll
            for (int i = 0; i < 4; i++)
                af[i] = *(const bf16x8*)&As[cur][mb + i*16 + l16][fc];
            #pragma unroll
            for (int j = 0; j < 4; j++)
                bfr[j] = *(const bf16x8*)&Bs[cur][nb + j*16 + l16][fc];

            #pragma unroll
            for (int i = 0; i < 4; i++)
                #pragma unroll
                for (int j = 0; j < 4; j++)
                    acc[i][j] = __builtin_amdgcn_mfma_f32_16x16x32_bf16(
                        af[i], bfr[j], acc[i][j], 0, 0, 0);
        }

        if (have_next) {
            // this wave's ds_reads must COMPLETE (not just issue) before
            // any wave's next STAGE overwrites buf[cur]; lgkmcnt leaves
            // the 8 prefetch GLPs (vmcnt) in flight
            asm volatile("s_waitcnt lgkmcnt(0)" ::: "memory");
            __builtin_amdgcn_s_barrier();
        }
    }

    if (MODE == 0) {
        #pragma unroll
        for (int j = 0; j < 4; j++) {
            const int n = n0 + nb + j*16 + l16;
            const float bv = bias[n];
            #pragma unroll
            for (int i = 0; i < 4; i++) {
                #pragma unroll
                for (int r = 0; r < 4; r++) {
                    const int m = m0 + mb + i*16 + quad*4 + r;
                    ((float*)outv)[(size_t)m * N + n] = acc[i][j][r] + bv;
                }
            }
        }
    } else {
        const int sec = n0 >> 10;        // block-uniform: 0=q 1=k 2=v
        const int b   = m0 >> 11;        // block-uniform batch index
        const int tb  = m0 & 2047;
        if (sec < 2) {
            // Q/K: [b,h,t,hd] layout; hd = l16-contiguous (32B runs)
            const float qs = (sec == 0) ? QSCALE : 1.f;
            #pragma unroll
            for (int j = 0; j < 4; j++) {
                const int n  = n0 + nb + j*16 + l16;
                const float bv = bias[n];
                const int dd = n & 1023;
                const int h  = dd >> 6;
                const int hd = dd & 63;
                u16* op = (u16*)outv + (size_t)sec * HEADELEMS
                        + ((size_t)(b*NH_ + h)) * T_ * HD_ + hd;
                #pragma unroll
                for (int i = 0; i < 4; i++) {
                    #pragma unroll
                    for (int r = 0; r < 4; r++) {
                        const int tt = tb + mb + i*16 + quad*4 + r;
                        op[(size_t)tt * HD_] = f2bf((acc[i][j][r] + bv) * qs);
                    }
                }
            }
        } else {
            // V^T: [b,h,hd,t] layout; 4 consecutive r == consecutive tt ->
            // one 8B store each
            #pragma unroll
            for (int j = 0; j < 4; j++) {
                const int n  = n0 + nb + j*16 + l16;
                const float bv = bias[n];
                const int dd = n & 1023;
                const int h  = dd >> 6;
                const int hd = dd & 63;
                u16* vp = (u16*)outv + (size_t)2 * HEADELEMS
                        + ((size_t)(b*NH_ + h)) * T_ * HD_
                        + (size_t)hd * T_ + tb + mb;
                #pragma unroll
                for (int i = 0; i < 4; i++) {
                    u16 o[4];
                    #pragma unroll
                    for (int r = 0; r < 4; r++) o[r] = f2bf(acc[i][j][r] + bv);
                    *(uint2*)(vp + i*16 + quad*4) = *(const uint2*)o;
                }
            }
        }
    }
}

// ---------------------------------------------------------------------------
// MFMA flash attention v7 (r7 config, kept: bank-conflict-free [64][64]
// XOR-seg layout, T5 setprio, balanced qt pairing, in-register C->A
// shuffles, ones-MFMA row sums, compile-time masked-tile split).
// ---------------------------------------------------------------------------
__global__ __launch_bounds__(256)
void attn_mfma_kernel(const u16* __restrict__ Q, const u16* __restrict__ K,
                      const u16* __restrict__ VT, u16* __restrict__ y1)
{
    __shared__ u16 Ks[2][64][64];     // [buf][key][d]   (XOR-seg swizzled)
    __shared__ u16 Vs[2][64][64];     // [buf][d][key]   (XOR-seg swizzled)

    const int t    = threadIdx.x;
    const int wave = t >> 6;
    const int lane = t & 63;
    const int l16  = lane & 15;
    const int quad = lane >> 4;

    const int hb = blockIdx.x;                 // b*NH + h (XCD-pinned)
    const int yy = blockIdx.y;
    const int a  = yy & 7, g = yy >> 3;
    const int qt = (g == 0) ? 31 - a : (g == 1) ? 16 + a
                 : (g == 2) ? 15 - a : a;      // balanced 4-way pairing
    const int b  = hb >> 4;
    const int h  = hb & 15;
    const size_t base = (size_t)hb * T_ * HD_;

    const int qw0 = qt * 64 + wave * 16;       // first q-row of this wave

    // Q fragment: 2 d-chunks (Q pre-scaled by QSCALE)
    bf16x8 qf[2];
    {
        const u16* qp = Q + base + (size_t)(qw0 + l16) * HD_ + quad * 8;
        qf[0] = *(const bf16x8*)(qp);
        qf[1] = *(const bf16x8*)(qp + 32);
    }

    bf16x8 onesf;
    #pragma unroll
    for (int i = 0; i < 8; i++) onesf[i] = (short)0x3F80;

    f32x4 o[4];
    #pragma unroll
    for (int d = 0; d < 4; d++) o[d] = (f32x4){0,0,0,0};
    f32x4 accl = (f32x4){0,0,0,0};

    const int nsteps = qt + 1;                 // uniform across waves

    const int srow = t >> 3;                   // 0..31
    const int scol = (t & 7) * 8;              // logical seg * 8
    const int sst  = (((t & 7) ^ (srow & 7)) * 8);  // stored (swizzled) col

    // fragment-read swizzled columns
    const int fs0 = (quad ^ (l16 & 7)) * 8;
    const int fs1 = fs0 ^ 32;

    // shuffle sources for C->A redistribution (r10-verified)
    const int srcA  = l16 + ((quad & 1) << 5);
    const int srcB  = srcA + 16;
    const bool selhi = (quad >> 1) != 0;

    // stage tile 0
    uint4 kr0, kr1, vr0, vr1;
    {
        const u16* kp = K + base + (size_t)srow * HD_ + scol;
        kr0 = *(const uint4*)kp;
        kr1 = *(const uint4*)(kp + 32 * HD_);
        const u16* vp = VT + base + (size_t)srow * T_ + scol;
        vr0 = *(const uint4*)vp;
        vr1 = *(const uint4*)(vp + 32 * T_);
        *(uint4*)&Ks[0][srow][sst]      = kr0;
        *(uint4*)&Ks[0][srow + 32][sst] = kr1;
        *(uint4*)&Vs[0][srow][sst]      = vr0;
        *(uint4*)&Vs[0][srow + 32][sst] = vr1;
    }
    __syncthreads();

    auto compute_tile = [&](int cur, int k0, auto mc) {
        constexpr bool MASKED = decltype(mc)::value;
        // S^T = K_tile . Q^T
        f32x4 st[4];
        __builtin_amdgcn_s_setprio(1);
        #pragma unroll
        for (int j = 0; j < 4; j++) {
            bf16x8 kf0 = *(const bf16x8*)&Ks[cur][j*16 + l16][fs0];
            bf16x8 kf1 = *(const bf16x8*)&Ks[cur][j*16 + l16][fs1];
            f32x4 z = {0,0,0,0};
            z = __builtin_amdgcn_mfma_f32_16x16x32_bf16(kf0, qf[0], z, 0, 0, 0);
            st[j] = __builtin_amdgcn_mfma_f32_16x16x32_bf16(kf1, qf[1], z, 0, 0, 0);
        }
        __builtin_amdgcn_s_setprio(0);

        // exp2 (+ mask, compile-time gated) + packed bf16
        u32 p01[4], p23[4];
        const int qi = qw0 + l16;
        #pragma unroll
        for (int j = 0; j < 4; j++) {
            const int kb = k0 + j*16 + quad*4;
            float e0 = __builtin_amdgcn_exp2f(st[j][0]);
            float e1 = __builtin_amdgcn_exp2f(st[j][1]);
            float e2 = __builtin_amdgcn_exp2f(st[j][2]);
            float e3 = __builtin_amdgcn_exp2f(st[j][3]);
            if (MASKED) {
                if (kb + 0 > qi) e0 = 0.f;
                if (kb + 1 > qi) e1 = 0.f;
                if (kb + 2 > qi) e2 = 0.f;
                if (kb + 3 > qi) e3 = 0.f;
            }
            p01[j] = pkbf2(e0, e1);
            p23[j] = pkbf2(e2, e3);
        }

        // C->A redistribution via shuffles; then ones-MFMA + PV
        bf16x8 pf[2];
        #pragma unroll
        for (int c = 0; c < 2; c++) {
            u32 t0, t1, r01, r23, r45, r67;
            t0 = (u32)__shfl((int)p01[2*c],   srcA);
            t1 = (u32)__shfl((int)p01[2*c+1], srcA);
            r01 = selhi ? t1 : t0;
            t0 = (u32)__shfl((int)p23[2*c],   srcA);
            t1 = (u32)__shfl((int)p23[2*c+1], srcA);
            r23 = selhi ? t1 : t0;
            t0 = (u32)__shfl((int)p01[2*c],   srcB);
            t1 = (u32)__shfl((int)p01[2*c+1], srcB);
            r45 = selhi ? t1 : t0;
            t0 = (u32)__shfl((int)p23[2*c],   srcB);
            t1 = (u32)__shfl((int)p23[2*c+1], srcB);
            r67 = selhi ? t1 : t0;
            union { u32 u[4]; bf16x8 v; } pk;
            pk.u[0] = r01; pk.u[1] = r23; pk.u[2] = r45; pk.u[3] = r67;
            pf[c] = pk.v;
        }
        __builtin_amdgcn_s_setprio(1);
        accl = __builtin_amdgcn_mfma_f32_16x16x32_bf16(pf[0], onesf, accl, 0, 0, 0);
        accl = __builtin_amdgcn_mfma_f32_16x16x32_bf16(pf[1], onesf, accl, 0, 0, 0);
        #pragma unroll
        for (int d = 0; d < 4; d++) {
            bf16x8 v0 = *(const bf16x8*)&Vs[cur][d*16 + l16][fs0];
            bf16x8 v1 = *(const bf16x8*)&Vs[cur][d*16 + l16][fs1];
            o[d] = __builtin_amdgcn_mfma_f32_16x16x32_bf16(pf[0], v0, o[d], 0, 0, 0);
            o[d] = __builtin_amdgcn_mfma_f32_16x16x32_bf16(pf[1], v1, o[d], 0, 0, 0);
        }
        __builtin_amdgcn_s_setprio(0);
    };

    for (int kt = 0; kt < nsteps; kt++) {
        const int cur = kt & 1;
        const int k0  = kt * 64;
        const bool have_next = (kt + 1 < nsteps);

        if (have_next) {
            const u16* kp = K + base + (size_t)(k0 + 64 + srow) * HD_ + scol;
            kr0 = *(const uint4*)kp;
            kr1 = *(const uint4*)(kp + 32 * HD_);
            const u16* vp = VT + base + (size_t)srow * T_ + k0 + 64 + scol;
            vr0 = *(const uint4*)vp;
            vr1 = *(const uint4*)(vp + 32 * T_);
        }

        if (kt < qt) compute_tile(cur, k0, Fc{});
        else         compute_tile(cur, k0, Tc{});

        if (have_next) {
            const int nxt = cur ^ 1;
            *(uint4*)&Ks[nxt][srow][sst]      = kr0;
            *(uint4*)&Ks[nxt][srow + 32][sst] = kr1;
            *(uint4*)&Vs[nxt][srow][sst]      = vr0;
            *(uint4*)&Vs[nxt][srow + 32][sst] = vr1;
            __syncthreads();
        }
    }

    // epilogue: normalize by ones-MFMA row sums; y1[B,T,D] bf16
    #pragma unroll
    for (int r = 0; r < 4; r++) {
        const float inv = 1.f / accl[r];
        const int qi = qw0 + quad*4 + r;
        u16* yp = y1 + ((size_t)(b * T_ + qi)) * D_ + h * HD_ + l16;
        yp[0]  = f2bf(o[0][r] * inv);
        yp[16] = f2bf(o[1][r] * inv);
        yp[32] = f2bf(o[2][r] * inv);
        yp[48] = f2bf(o[3][r] * inv);
    }
}

// ---------------------------------------------------------------------------
// Choreography, three ws tiers:
//  huge (>= 3*QKV + y1 + WprojT = ~35.7 MB): prep also transposes Wproj into
//    ws; attn -> y1 in ws; 4 dispatches, no memcpy.
//  big  (>= 3*QKV + y1 = ~33.5 MB): y1 in ws; WprojT over dead K after attn.
//  small: y1 over dead xb in d_out; memcpy to dead VT; WprojT over dead K.
// ---------------------------------------------------------------------------
extern "C" void kernel_launch(void* const* d_in, const int* in_sizes, int n_in,
                              void* d_out, int out_size, void* d_ws, size_t ws_size,
                              hipStream_t stream)
{
    const float* x     = (const float*)d_in[0];
    const float* Wqkv  = (const float*)d_in[1];
    const float* bqkv  = (const float*)d_in[2];
    const float* Wproj = (const float*)d_in[3];
    const float* bproj = (const float*)d_in[4];

    u16* scratch = (u16*)d_out;
    u16* xb      = scratch;
    u16* WqkvT   = scratch + (size_t)MROWS * D_;

    const size_t Y1E = (size_t)MROWS * D_;   // y1 elems (== HEADELEMS)
    const size_t WPE = (size_t)D_ * D_;      // WprojT elems

    u16* qkv = (u16*)d_ws;
    u16* Qp  = qkv;
    u16* Kp  = qkv + (size_t)HEADELEMS;
    u16* Vtp = qkv + (size_t)2 * HEADELEMS;

    const bool huge = ws_size >= ((size_t)3 * HEADELEMS + Y1E + WPE) * 2;
    const bool big  = ws_size >= ((size_t)3 * HEADELEMS + Y1E) * 2;

    u16* y1b    = big ? qkv + (size_t)3 * HEADELEMS : scratch;
    u16* y1g    = big ? y1b : Vtp;
    u16* WprojT = huge ? qkv + (size_t)3 * HEADELEMS + Y1E : Kp;

    // 1) fused prep
    prep_kernel<<<huge ? 5120 : 4864, 256, 0, stream>>>(
        x, Wqkv, Wproj, xb, WqkvT, WprojT);

    // 2) QKV GEMM -> Q(prescaled) | K | VT (bf16) in ws; 1D 768 blocks,
    //    bijective XCD swizzle inside
    gemm_mfma<1><<<768, 256, 0, stream>>>(
        xb, WqkvT, bqkv, (void*)qkv, MROWS, 3*D_, D_);

    // 3) attention -> y1 bf16; grid (hb=32, y=32), 64 q-rows/block
    attn_mfma_kernel<<<dim3(NH_*B_, T_/64), 256, 0, stream>>>(Qp, Kp, Vtp, y1b);

    // 4) Wproj transpose (non-huge paths; K dead now)
    if (!huge)
        transpose_conv_kernel<<<dim3(D_/64, D_/64), 256, 0, stream>>>(
            Wproj, WprojT, D_, D_);

    // 5) small-ws fallback: move y1 out of d_out
    if (!big)
        (void)hipMemcpyAsync(y1g, y1b, Y1E * sizeof(u16),
                             hipMemcpyDeviceToDevice, stream);

    // 6) output projection -> fp32 d_out; 1D 256 blocks, XCD swizzle inside
    gemm_mfma<0><<<256, 256, 0, stream>>>(
        y1g, WprojT, bproj, d_out, MROWS, D_, D_);
}

// Round 10
// 190.141 us; speedup vs baseline: 1.0957x; 1.0229x over previous
//
#include <hip/hip_runtime.h>
#include <hip/hip_bf16.h>

// Problem constants
#define B_   2
#define T_   2048
#define D_   1024
#define NH_  16
#define HD_  64
#define MROWS (B_*T_)              // 4096
#define HEADELEMS (B_*NH_*T_*HD_)  // 4194304 per Q/K/V tensor

// exp(s/8) = 2^(s * 0.125 * log2 e); folded into Q at the QKV epilogue
#define QSCALE 0.180336880f

typedef unsigned short u16;
typedef unsigned int   u32;

typedef float f32x4  __attribute__((ext_vector_type(4)));
typedef short bf16x8 __attribute__((ext_vector_type(8)));

// async global->LDS, 16 B/lane; LDS dest MUST be wave-uniform (base+lane*16)
#define GLP(g, l) __builtin_amdgcn_global_load_lds(                         \
    (const __attribute__((address_space(1))) void*)(g),                     \
    (__attribute__((address_space(3))) void*)(l), 16, 0, 0)

struct Fc { static constexpr bool value = false; };
struct Tc { static constexpr bool value = true;  };

__device__ __forceinline__ u16 f2bf(float f) {
    u32 x = __float_as_uint(f);
    u32 r = (x + 0x7fffu + ((x >> 16) & 1u)) >> 16;
    return (u16)r;
}
// packed fp32x2 -> bf16x2
__device__ __forceinline__ u32 pkbf2(float a, float b) {
    __hip_bfloat162 h = __float22bfloat162_rn(make_float2(a, b));
    union { __hip_bfloat162 h2; u32 u; } cv; cv.h2 = h; return cv.u;
}

// ---------------------------------------------------------------------------
// Fused prep: [0,4096) x fp32->bf16; [4096,4864) Wqkv -> bf16 T;
// [4864,5120) Wproj -> bf16 T (only launched on the huge-ws path).
// ---------------------------------------------------------------------------
__device__ __forceinline__ void transpose_tile(const float* in, u16* out,
                                               int K, int N, int bx, int by,
                                               int t, float (*Ts)[65])
{
    const int n0 = bx * 64;
    const int k0 = by * 64;
    #pragma unroll
    for (int pass = 0; pass < 4; pass++) {
        const int r = pass * 16 + (t >> 4);
        const int c = (t & 15) * 4;
        float4 v = *(const float4*)(in + (size_t)(k0 + r) * N + n0 + c);
        Ts[r][c] = v.x; Ts[r][c+1] = v.y; Ts[r][c+2] = v.z; Ts[r][c+3] = v.w;
    }
    __syncthreads();
    #pragma unroll
    for (int pass = 0; pass < 2; pass++) {
        const int nn = pass * 32 + (t >> 3);
        const int kk = (t & 7) * 8;
        u16 o[8];
        #pragma unroll
        for (int j = 0; j < 8; j++) o[j] = f2bf(Ts[kk + j][nn]);
        *(uint4*)(out + (size_t)(n0 + nn) * K + k0 + kk) = *(const uint4*)o;
    }
}

__global__ __launch_bounds__(256)
void prep_kernel(const float* __restrict__ x, const float* __restrict__ Wqkv,
                 const float* __restrict__ Wproj, u16* __restrict__ xb,
                 u16* __restrict__ WqkvT, u16* __restrict__ WprojT)
{
    __shared__ float Ts[64][65];
    const int bid = blockIdx.x;
    const int t   = threadIdx.x;
    if (bid < 4096) {
        int i = bid * 256 + t;
        float4 v = ((const float4*)x)[i];
        ushort4 o;
        o.x = f2bf(v.x); o.y = f2bf(v.y); o.z = f2bf(v.z); o.w = f2bf(v.w);
        ((ushort4*)xb)[i] = o;
    } else if (bid < 4096 + 768) {
        int tb = bid - 4096;                   // [3072][1024] T
        transpose_tile(Wqkv, WqkvT, D_, 3*D_, tb % 48, tb / 48, t, Ts);
    } else {
        int tb = bid - 4864;                   // [1024][1024] T
        transpose_tile(Wproj, WprojT, D_, D_, tb % 16, tb / 16, t, Ts);
    }
}

__global__ __launch_bounds__(256)
void transpose_conv_kernel(const float* __restrict__ in, u16* __restrict__ out,
                           int K, int N)
{
    __shared__ float Ts[64][65];
    transpose_tile(in, out, K, N, blockIdx.x, blockIdx.y, threadIdx.x, Ts);
}

// ---------------------------------------------------------------------------
// MFMA GEMM, round-18: A/B isolation of r9's two changes. KEEP the
// counted-vmcnt double-buffered pipeline (r9 counters: VALUBusy 27.8->15.5
// at constant MfmaUtil -> pipeline healthy); REVERT the XCD swizzle, whose
// n-panel-major chunking put all 32 A-panels (8 MB) in each XCD's 4 MB L2
// (FETCH_SIZE 40 -> 68.7 MB, the r9 regression). Back to the proven 2D
// grid (bx = N-panel fastest, 40 MB FETCH in r0-r7).
// Pipeline per K-step: STAGE(buf^1, k+1) -> vmcnt(8) (tile k's loads only;
// the 8 new stay in flight across the barrier, never drain 0 in-loop) ->
// s_barrier -> ds_read + 32 MFMA -> lgkmcnt(0) + s_barrier.
// Staging: per-lane global row srow=t>>3, pre-swizzled seg ((t&7)^(srow&7));
// wave-uniform LDS base wave*8 (+32/64/96). Stored seg s at row r holds
// logical s^(r&7); frag read col (quad^(l16&7))*8 ^ (kk*32). Conflicts = 0
// (r9-verified).
// MODE 0: fp32 row-major + bias. MODE 1: scatter bf16 Q(*QSCALE),K | V^T.
// ---------------------------------------------------------------------------
template <int MODE>
__global__ __launch_bounds__(256)
void gemm_mfma(const u16* __restrict__ A, const u16* __restrict__ BT,
               const float* __restrict__ bias, void* __restrict__ outv,
               int M, int N, int K)
{
    __shared__ u16 As[2][128][64];
    __shared__ u16 Bs[2][128][64];

    const int t    = threadIdx.x;
    const int wave = t >> 6;
    const int lane = t & 63;
    const int l16  = lane & 15;
    const int quad = lane >> 4;

    const int m0 = blockIdx.y * 128;
    const int n0 = blockIdx.x * 128;
    const int mb = (wave >> 1) * 64;
    const int nb = (wave & 1) * 64;

    // staging: per-lane GLOBAL address (row srow, pre-swizzled seg);
    // wave-uniform LDS base rw8 (+32/64/96)
    const int srow = t >> 3;                     // 0..31 (block-wide)
    const int sseg = ((t & 7) ^ (srow & 7)) * 8; // pre-swizzled k-offset
    const int rw8  = wave * 8;                   // wave-uniform LDS row base

    const u16* gA = A  + (size_t)(m0 + srow) * K + sseg;
    const u16* gB = BT + (size_t)(n0 + srow) * K + sseg;

    // frag read col: logical chunk quad (kk=0) / quad+4 (kk=1), row&7==l16&7
    const int fragcol = (quad ^ (l16 & 7)) * 8;

    f32x4 acc[4][4];
    #pragma unroll
    for (int i = 0; i < 4; i++)
        #pragma unroll
        for (int j = 0; j < 4; j++) acc[i][j] = (f32x4){0,0,0,0};

    // one tile = 8 GLPs (A 4x32 rows, B 4x32 rows); each GLP: 64 lanes x
    // 16B = rows [base, base+8) of 128B
    auto STAGE = [&](int buf, int k0) {
        GLP(gA + k0,          &As[buf][rw8     ][0]);
        GLP(gA + k0 + 32*K,   &As[buf][rw8 + 32][0]);
        GLP(gA + k0 + 64*K,   &As[buf][rw8 + 64][0]);
        GLP(gA + k0 + 96*K,   &As[buf][rw8 + 96][0]);
        GLP(gB + k0,          &Bs[buf][rw8     ][0]);
        GLP(gB + k0 + 32*K,   &Bs[buf][rw8 + 32][0]);
        GLP(gB + k0 + 64*K,   &Bs[buf][rw8 + 64][0]);
        GLP(gB + k0 + 96*K,   &Bs[buf][rw8 + 96][0]);
    };

    const int nk = K >> 6;

    // prologue: tile 0 -> buf 0, full drain once
    STAGE(0, 0);
    asm volatile("s_waitcnt vmcnt(0)" ::: "memory");
    __builtin_amdgcn_s_barrier();

    for (int kt = 0; kt < nk; ++kt) {
        const int cur = kt & 1;
        const bool have_next = (kt + 1 < nk);

        if (have_next) {
            STAGE(cur ^ 1, (kt + 1) << 6);
            // wait ONLY tile kt's 8 loads; the 8 just-issued stay in flight
            asm volatile("s_waitcnt vmcnt(8)" ::: "memory");
        } else {
            asm volatile("s_waitcnt vmcnt(0)" ::: "memory");
        }
        __builtin_amdgcn_s_barrier();

        #pragma unroll
        for (int kk = 0; kk < 2; kk++) {
            const int fc = fragcol ^ (kk << 5);
            bf16x8 af[4], bfr[4];
            #pragma unroll
            for (int i = 0; i < 4; i++)
                af[i] = *(const bf16x8*)&As[cur][mb + i*16 + l16][fc];
            #pragma unroll
            for (int j = 0; j < 4; j++)
                bfr[j] = *(const bf16x8*)&Bs[cur][nb + j*16 + l16][fc];

            #pragma unroll
            for (int i = 0; i < 4; i++)
                #pragma unroll
                for (int j = 0; j < 4; j++)
                    acc[i][j] = __builtin_amdgcn_mfma_f32_16x16x32_bf16(
                        af[i], bfr[j], acc[i][j], 0, 0, 0);
        }

        if (have_next) {
            // this wave's ds_reads must COMPLETE before any wave's next
            // STAGE overwrites buf[cur]; lgkmcnt leaves the 8 prefetch
            // GLPs (vmcnt) in flight
            asm volatile("s_waitcnt lgkmcnt(0)" ::: "memory");
            __builtin_amdgcn_s_barrier();
        }
    }

    if (MODE == 0) {
        #pragma unroll
        for (int j = 0; j < 4; j++) {
            const int n = n0 + nb + j*16 + l16;
            const float bv = bias[n];
            #pragma unroll
            for (int i = 0; i < 4; i++) {
                #pragma unroll
                for (int r = 0; r < 4; r++) {
                    const int m = m0 + mb + i*16 + quad*4 + r;
                    ((float*)outv)[(size_t)m * N + n] = acc[i][j][r] + bv;
                }
            }
        }
    } else {
        const int sec = n0 >> 10;        // block-uniform: 0=q 1=k 2=v
        const int b   = m0 >> 11;        // block-uniform batch index
        const int tb  = m0 & 2047;
        if (sec < 2) {
            // Q/K: [b,h,t,hd] layout; hd = l16-contiguous (32B runs)
            const float qs = (sec == 0) ? QSCALE : 1.f;
            #pragma unroll
            for (int j = 0; j < 4; j++) {
                const int n  = n0 + nb + j*16 + l16;
                const float bv = bias[n];
                const int dd = n & 1023;
                const int h  = dd >> 6;
                const int hd = dd & 63;
                u16* op = (u16*)outv + (size_t)sec * HEADELEMS
                        + ((size_t)(b*NH_ + h)) * T_ * HD_ + hd;
                #pragma unroll
                for (int i = 0; i < 4; i++) {
                    #pragma unroll
                    for (int r = 0; r < 4; r++) {
                        const int tt = tb + mb + i*16 + quad*4 + r;
                        op[(size_t)tt * HD_] = f2bf((acc[i][j][r] + bv) * qs);
                    }
                }
            }
        } else {
            // V^T: [b,h,hd,t] layout; 4 consecutive r == consecutive tt ->
            // one 8B store each
            #pragma unroll
            for (int j = 0; j < 4; j++) {
                const int n  = n0 + nb + j*16 + l16;
                const float bv = bias[n];
                const int dd = n & 1023;
                const int h  = dd >> 6;
                const int hd = dd & 63;
                u16* vp = (u16*)outv + (size_t)2 * HEADELEMS
                        + ((size_t)(b*NH_ + h)) * T_ * HD_
                        + (size_t)hd * T_ + tb + mb;
                #pragma unroll
                for (int i = 0; i < 4; i++) {
                    u16 o[4];
                    #pragma unroll
                    for (int r = 0; r < 4; r++) o[r] = f2bf(acc[i][j][r] + bv);
                    *(uint2*)(vp + i*16 + quad*4) = *(const uint2*)o;
                }
            }
        }
    }
}

// ---------------------------------------------------------------------------
// MFMA flash attention v7 (r7 config, kept: bank-conflict-free [64][64]
// XOR-seg layout, T5 setprio, balanced qt pairing, in-register C->A
// shuffles, ones-MFMA row sums, compile-time masked-tile split).
// ---------------------------------------------------------------------------
__global__ __launch_bounds__(256)
void attn_mfma_kernel(const u16* __restrict__ Q, const u16* __restrict__ K,
                      const u16* __restrict__ VT, u16* __restrict__ y1)
{
    __shared__ u16 Ks[2][64][64];     // [buf][key][d]   (XOR-seg swizzled)
    __shared__ u16 Vs[2][64][64];     // [buf][d][key]   (XOR-seg swizzled)

    const int t    = threadIdx.x;
    const int wave = t >> 6;
    const int lane = t & 63;
    const int l16  = lane & 15;
    const int quad = lane >> 4;

    const int hb = blockIdx.x;                 // b*NH + h (XCD-pinned)
    const int yy = blockIdx.y;
    const int a  = yy & 7, g = yy >> 3;
    const int qt = (g == 0) ? 31 - a : (g == 1) ? 16 + a
                 : (g == 2) ? 15 - a : a;      // balanced 4-way pairing
    const int b  = hb >> 4;
    const int h  = hb & 15;
    const size_t base = (size_t)hb * T_ * HD_;

    const int qw0 = qt * 64 + wave * 16;       // first q-row of this wave

    // Q fragment: 2 d-chunks (Q pre-scaled by QSCALE)
    bf16x8 qf[2];
    {
        const u16* qp = Q + base + (size_t)(qw0 + l16) * HD_ + quad * 8;
        qf[0] = *(const bf16x8*)(qp);
        qf[1] = *(const bf16x8*)(qp + 32);
    }

    bf16x8 onesf;
    #pragma unroll
    for (int i = 0; i < 8; i++) onesf[i] = (short)0x3F80;

    f32x4 o[4];
    #pragma unroll
    for (int d = 0; d < 4; d++) o[d] = (f32x4){0,0,0,0};
    f32x4 accl = (f32x4){0,0,0,0};

    const int nsteps = qt + 1;                 // uniform across waves

    const int srow = t >> 3;                   // 0..31
    const int scol = (t & 7) * 8;              // logical seg * 8
    const int sst  = (((t & 7) ^ (srow & 7)) * 8);  // stored (swizzled) col

    // fragment-read swizzled columns
    const int fs0 = (quad ^ (l16 & 7)) * 8;
    const int fs1 = fs0 ^ 32;

    // shuffle sources for C->A redistribution (r10-verified)
    const int srcA  = l16 + ((quad & 1) << 5);
    const int srcB  = srcA + 16;
    const bool selhi = (quad >> 1) != 0;

    // stage tile 0
    uint4 kr0, kr1, vr0, vr1;
    {
        const u16* kp = K + base + (size_t)srow * HD_ + scol;
        kr0 = *(const uint4*)kp;
        kr1 = *(const uint4*)(kp + 32 * HD_);
        const u16* vp = VT + base + (size_t)srow * T_ + scol;
        vr0 = *(const uint4*)vp;
        vr1 = *(const uint4*)(vp + 32 * T_);
        *(uint4*)&Ks[0][srow][sst]      = kr0;
        *(uint4*)&Ks[0][srow + 32][sst] = kr1;
        *(uint4*)&Vs[0][srow][sst]      = vr0;
        *(uint4*)&Vs[0][srow + 32][sst] = vr1;
    }
    __syncthreads();

    auto compute_tile = [&](int cur, int k0, auto mc) {
        constexpr bool MASKED = decltype(mc)::value;
        // S^T = K_tile . Q^T
        f32x4 st[4];
        __builtin_amdgcn_s_setprio(1);
        #pragma unroll
        for (int j = 0; j < 4; j++) {
            bf16x8 kf0 = *(const bf16x8*)&Ks[cur][j*16 + l16][fs0];
            bf16x8 kf1 = *(const bf16x8*)&Ks[cur][j*16 + l16][fs1];
            f32x4 z = {0,0,0,0};
            z = __builtin_amdgcn_mfma_f32_16x16x32_bf16(kf0, qf[0], z, 0, 0, 0);
            st[j] = __builtin_amdgcn_mfma_f32_16x16x32_bf16(kf1, qf[1], z, 0, 0, 0);
        }
        __builtin_amdgcn_s_setprio(0);

        // exp2 (+ mask, compile-time gated) + packed bf16
        u32 p01[4], p23[4];
        const int qi = qw0 + l16;
        #pragma unroll
        for (int j = 0; j < 4; j++) {
            const int kb = k0 + j*16 + quad*4;
            float e0 = __builtin_amdgcn_exp2f(st[j][0]);
            float e1 = __builtin_amdgcn_exp2f(st[j][1]);
            float e2 = __builtin_amdgcn_exp2f(st[j][2]);
            float e3 = __builtin_amdgcn_exp2f(st[j][3]);
            if (MASKED) {
                if (kb + 0 > qi) e0 = 0.f;
                if (kb + 1 > qi) e1 = 0.f;
                if (kb + 2 > qi) e2 = 0.f;
                if (kb + 3 > qi) e3 = 0.f;
            }
            p01[j] = pkbf2(e0, e1);
            p23[j] = pkbf2(e2, e3);
        }

        // C->A redistribution via shuffles; then ones-MFMA + PV
        bf16x8 pf[2];
        #pragma unroll
        for (int c = 0; c < 2; c++) {
            u32 t0, t1, r01, r23, r45, r67;
            t0 = (u32)__shfl((int)p01[2*c],   srcA);
            t1 = (u32)__shfl((int)p01[2*c+1], srcA);
            r01 = selhi ? t1 : t0;
            t0 = (u32)__shfl((int)p23[2*c],   srcA);
            t1 = (u32)__shfl((int)p23[2*c+1], srcA);
            r23 = selhi ? t1 : t0;
            t0 = (u32)__shfl((int)p01[2*c],   srcB);
            t1 = (u32)__shfl((int)p01[2*c+1], srcB);
            r45 = selhi ? t1 : t0;
            t0 = (u32)__shfl((int)p23[2*c],   srcB);
            t1 = (u32)__shfl((int)p23[2*c+1], srcB);
            r67 = selhi ? t1 : t0;
            union { u32 u[4]; bf16x8 v; } pk;
            pk.u[0] = r01; pk.u[1] = r23; pk.u[2] = r45; pk.u[3] = r67;
            pf[c] = pk.v;
        }
        __builtin_amdgcn_s_setprio(1);
        accl = __builtin_amdgcn_mfma_f32_16x16x32_bf16(pf[0], onesf, accl, 0, 0, 0);
        accl = __builtin_amdgcn_mfma_f32_16x16x32_bf16(pf[1], onesf, accl, 0, 0, 0);
        #pragma unroll
        for (int d = 0; d < 4; d++) {
            bf16x8 v0 = *(const bf16x8*)&Vs[cur][d*16 + l16][fs0];
            bf16x8 v1 = *(const bf16x8*)&Vs[cur][d*16 + l16][fs1];
            o[d] = __builtin_amdgcn_mfma_f32_16x16x32_bf16(pf[0], v0, o[d], 0, 0, 0);
            o[d] = __builtin_amdgcn_mfma_f32_16x16x32_bf16(pf[1], v1, o[d], 0, 0, 0);
        }
        __builtin_amdgcn_s_setprio(0);
    };

    for (int kt = 0; kt < nsteps; kt++) {
        const int cur = kt & 1;
        const int k0  = kt * 64;
        const bool have_next = (kt + 1 < nsteps);

        if (have_next) {
            const u16* kp = K + base + (size_t)(k0 + 64 + srow) * HD_ + scol;
            kr0 = *(const uint4*)kp;
            kr1 = *(const uint4*)(kp + 32 * HD_);
            const u16* vp = VT + base + (size_t)srow * T_ + k0 + 64 + scol;
            vr0 = *(const uint4*)vp;
            vr1 = *(const uint4*)(vp + 32 * T_);
        }

        if (kt < qt) compute_tile(cur, k0, Fc{});
        else         compute_tile(cur, k0, Tc{});

        if (have_next) {
            const int nxt = cur ^ 1;
            *(uint4*)&Ks[nxt][srow][sst]      = kr0;
            *(uint4*)&Ks[nxt][srow + 32][sst] = kr1;
            *(uint4*)&Vs[nxt][srow][sst]      = vr0;
            *(uint4*)&Vs[nxt][srow + 32][sst] = vr1;
            __syncthreads();
        }
    }

    // epilogue: normalize by ones-MFMA row sums; y1[B,T,D] bf16
    #pragma unroll
    for (int r = 0; r < 4; r++) {
        const float inv = 1.f / accl[r];
        const int qi = qw0 + quad*4 + r;
        u16* yp = y1 + ((size_t)(b * T_ + qi)) * D_ + h * HD_ + l16;
        yp[0]  = f2bf(o[0][r] * inv);
        yp[16] = f2bf(o[1][r] * inv);
        yp[32] = f2bf(o[2][r] * inv);
        yp[48] = f2bf(o[3][r] * inv);
    }
}

// ---------------------------------------------------------------------------
// Choreography, three ws tiers:
//  huge (>= 3*QKV + y1 + WprojT = ~35.7 MB): prep also transposes Wproj into
//    ws; attn -> y1 in ws; 4 dispatches, no memcpy.
//  big  (>= 3*QKV + y1 = ~33.5 MB): y1 in ws; WprojT over dead K after attn.
//  small: y1 over dead xb in d_out; memcpy to dead VT; WprojT over dead K.
// ---------------------------------------------------------------------------
extern "C" void kernel_launch(void* const* d_in, const int* in_sizes, int n_in,
                              void* d_out, int out_size, void* d_ws, size_t ws_size,
                              hipStream_t stream)
{
    const float* x     = (const float*)d_in[0];
    const float* Wqkv  = (const float*)d_in[1];
    const float* bqkv  = (const float*)d_in[2];
    const float* Wproj = (const float*)d_in[3];
    const float* bproj = (const float*)d_in[4];

    u16* scratch = (u16*)d_out;
    u16* xb      = scratch;
    u16* WqkvT   = scratch + (size_t)MROWS * D_;

    const size_t Y1E = (size_t)MROWS * D_;   // y1 elems (== HEADELEMS)
    const size_t WPE = (size_t)D_ * D_;      // WprojT elems

    u16* qkv = (u16*)d_ws;
    u16* Qp  = qkv;
    u16* Kp  = qkv + (size_t)HEADELEMS;
    u16* Vtp = qkv + (size_t)2 * HEADELEMS;

    const bool huge = ws_size >= ((size_t)3 * HEADELEMS + Y1E + WPE) * 2;
    const bool big  = ws_size >= ((size_t)3 * HEADELEMS + Y1E) * 2;

    u16* y1b    = big ? qkv + (size_t)3 * HEADELEMS : scratch;
    u16* y1g    = big ? y1b : Vtp;
    u16* WprojT = huge ? qkv + (size_t)3 * HEADELEMS + Y1E : Kp;

    // 1) fused prep
    prep_kernel<<<huge ? 5120 : 4864, 256, 0, stream>>>(
        x, Wqkv, Wproj, xb, WqkvT, WprojT);

    // 2) QKV GEMM -> Q(prescaled) | K | VT (bf16) in ws; 2D grid (proven
    //    L2 pattern, 40 MB FETCH), pipelined GEMM
    gemm_mfma<1><<<dim3(3*D_/128, MROWS/128), 256, 0, stream>>>(
        xb, WqkvT, bqkv, (void*)qkv, MROWS, 3*D_, D_);

    // 3) attention -> y1 bf16; grid (hb=32, y=32), 64 q-rows/block
    attn_mfma_kernel<<<dim3(NH_*B_, T_/64), 256, 0, stream>>>(Qp, Kp, Vtp, y1b);

    // 4) Wproj transpose (non-huge paths; K dead now)
    if (!huge)
        transpose_conv_kernel<<<dim3(D_/64, D_/64), 256, 0, stream>>>(
            Wproj, WprojT, D_, D_);

    // 5) small-ws fallback: move y1 out of d_out
    if (!big)
        (void)hipMemcpyAsync(y1g, y1b, Y1E * sizeof(u16),
                             hipMemcpyDeviceToDevice, stream);

    // 6) output projection -> fp32 d_out; 2D grid
    gemm_mfma<0><<<dim3(D_/128, MROWS/128), 256, 0, stream>>>(
        y1g, WprojT, bproj, d_out, MROWS, D_, D_);
}